// Round 2
// baseline (6620.227 us; speedup 1.0000x reference)
//
#include <hip/hip_runtime.h>

#define DD 128
#define BSZ 128
#define SEQL 128
#define TST 127
#define QNN 4
#define CNN 10
#define NQCC 4
#define RKK 10
#define NEGV -1000000000.0f

// ---- workspace float offsets ----
#define OFF_WTA0    0         // [128][128] W_agg0^T
#define OFF_WTA1    16384     // [128][128] W_agg1^T
#define OFF_WTAL    32768     // [128][128] W_agg_last^T
#define OFF_WTIH1A  49152     // [128][384] W_ih1[:, :128]^T
#define OFF_ERIH1   98304     // [2][384]   W_ih1[:,128:]@Er[r]
#define OFF_ECA0    99072     // [1000][128] W_agg0 @ Ec[c]
#define OFF_E1C     227072    // [1000][128] tanh(W_agg1@(cmean+Ec)+b1)
#define OFF_GI1     355072    // [16256][384]
#define OFF_TIX     6597376   // [16256][10] int
#define OFF_TMSK    6759936   // [16256][10] int
#define OFF_CID     6922496   // [16256][5] int
#define OFF_WPACK   7003776   // 90112 uint32 (bf16-pair packed weights)

__device__ __forceinline__ float sigm(float x) { return 1.0f / (1.0f + __expf(-x)); }
__device__ __forceinline__ float bl(unsigned u) { return __uint_as_float(u << 16); }
__device__ __forceinline__ float bh(unsigned u) { return __uint_as_float(u & 0xffff0000u); }
__device__ __forceinline__ unsigned f2b_bits(float f) {
  unsigned u = __float_as_uint(f);
  return (u + 0x7fffu + ((u >> 16) & 1u)) >> 16;
}
__device__ __forceinline__ unsigned short f2b(float f) { return (unsigned short)f2b_bits(f); }
__device__ __forceinline__ float dot8(float a, uint4 w, float4 x0, float4 x1) {
  a = fmaf(bl(w.x), x0.x, a); a = fmaf(bh(w.x), x0.y, a);
  a = fmaf(bl(w.y), x0.z, a); a = fmaf(bh(w.y), x0.w, a);
  a = fmaf(bl(w.z), x1.x, a); a = fmaf(bh(w.z), x1.y, a);
  a = fmaf(bl(w.w), x1.z, a); a = fmaf(bh(w.w), x1.w, a);
  return a;
}

// ---------------- K0a: fp32 tables + bf16 packed weight table ----------------
__global__ __launch_bounds__(256) void k_prep(
    const float* __restrict__ W_hh1, const float* __restrict__ W_ih2,
    const float* __restrict__ W_hh2, const float* __restrict__ Wq,
    const float* __restrict__ Wk, const float* __restrict__ W_agg,
    const float* __restrict__ W_agg_last, const float* __restrict__ W_ih1,
    const float* __restrict__ Er, float* __restrict__ ws) {
  int idx = blockIdx.x * 256 + threadIdx.x;
  const int TOT = 99072 + 90112;
  for (int o = idx; o < TOT; o += gridDim.x * 256) {
    if (o < 99072) {
      int r = o;
      if (r < 16384) { int j = r >> 7, i = r & 127; ws[o] = W_agg[i * 128 + j]; continue; }
      if (r < 32768) { r -= 16384; int j = r >> 7, i = r & 127; ws[o] = W_agg[16384 + i * 128 + j]; continue; }
      if (r < 49152) { r -= 32768; int j = r >> 7, i = r & 127; ws[o] = W_agg_last[i * 128 + j]; continue; }
      if (r < 98304) { r -= 49152; int j = r / 384, i = r % 384; ws[o] = W_ih1[i * 256 + j]; continue; }
      { r -= 98304; int rr = r / 384, i2 = r % 384;
        float a = 0.f;
        for (int j = 0; j < 128; ++j) a += Er[rr * 128 + j] * W_ih1[i2 * 256 + 128 + j];
        ws[o] = a; }
    } else {
      int w = o - 99072;
      int n = w & 3; int rest = w >> 2;
      int i = rest & 127; rest >>= 7;
      int kk = rest & 3; rest >>= 2;
      int jc = rest & 3; int c = rest >> 2;
      int j0 = jc * 32 + kk * 8 + n * 2;
      const float* row;
      if (c < 3) row = W_hh1 + (size_t)(c * 128 + i) * 128;
      else if (c < 6) row = W_ih2 + (size_t)((c - 3) * 128 + i) * 128;
      else if (c < 9) row = W_hh2 + (size_t)((c - 6) * 128 + i) * 128;
      else if (c == 9) row = Wq + (size_t)i * 128;
      else row = Wk + (size_t)i * 128;
      unsigned b0 = f2b_bits(row[j0]), b1 = f2b_bits(row[j0 + 1]);
      ((unsigned*)ws)[OFF_WPACK + w] = b0 | (b1 << 16);
    }
  }
}

// ---------------- K0b: per-concept tables ----------------
__global__ __launch_bounds__(128) void k_concept(
    const int* __restrict__ cnbr, const float* __restrict__ Eq,
    const float* __restrict__ Ec, const float* __restrict__ b_agg,
    float* __restrict__ ws) {
  int c = blockIdx.x;
  int tid = threadIdx.x;
  __shared__ int s_nb[CNN];
  __shared__ float s_v[DD], s_ec[DD];
  if (tid < CNN) s_nb[tid] = cnbr[c * CNN + tid];
  __syncthreads();
  float ec = Ec[c * DD + tid];
  float cm = 0.f;
#pragma unroll
  for (int l = 0; l < CNN; ++l) cm += Eq[(size_t)s_nb[l] * DD + tid];
  s_ec[tid] = ec;
  s_v[tid] = cm * 0.1f + ec;
  __syncthreads();
  const float* WtA0 = ws + OFF_WTA0;
  const float* WtA1 = ws + OFF_WTA1;
  float a1 = 0.f, a0 = 0.f;
#pragma unroll 8
  for (int j = 0; j < DD; ++j) {
    a1 += WtA1[j * DD + tid] * s_v[j];
    a0 += WtA0[j * DD + tid] * s_ec[j];
  }
  ws[OFF_E1C + c * DD + tid] = tanhf(a1 + b_agg[DD + tid]);
  ws[OFF_ECA0 + c * DD + tid] = a0;
}

// ---------------- K0c: per-(b,t) aggregation + gi1 ----------------
__global__ __launch_bounds__(128) void k_agg(
    const int* __restrict__ qseq, const int* __restrict__ rseq,
    const int* __restrict__ mseq, const int* __restrict__ qnbr,
    const float* __restrict__ Eq, const float* __restrict__ b_agg,
    const float* __restrict__ b_agg_last, const float* __restrict__ b_ih1,
    float* __restrict__ ws) {
  int bt = blockIdx.x;
  int b = bt / TST, t = bt - b * TST;
  int tid = threadIdx.x;
  __shared__ int s_n1[QNN];
  __shared__ int s_qrm[3];
  __shared__ float s_a[DD], s_b[DD], s_c[DD];
  if (tid < 3) s_qrm[tid] = (tid == 0) ? qseq[b * SEQL + t] : (tid == 1 ? rseq[b * SEQL + t] : mseq[b * SEQL + t]);
  __syncthreads();
  int q = s_qrm[0];
  if (tid < QNN) s_n1[tid] = qnbr[q * QNN + tid];
  s_a[tid] = Eq[(size_t)q * DD + tid];
  __syncthreads();
  const float* WtA0 = ws + OFF_WTA0;
  const float* WtAL = ws + OFF_WTAL;
  const float* WtIH1A = ws + OFF_WTIH1A;
  const float* EcA0 = ws + OFF_ECA0;
  const float* E1C = ws + OFF_E1C;
  float a = 0.f;
#pragma unroll 8
  for (int j = 0; j < DD; ++j) a += WtA0[j * DD + tid] * s_a[j];
  int n0 = s_n1[0], n1 = s_n1[1], n2 = s_n1[2], n3 = s_n1[3];
  float pre0 = 0.25f * (EcA0[n0 * DD + tid] + EcA0[n1 * DD + tid] + EcA0[n2 * DD + tid] + EcA0[n3 * DD + tid]);
  float e0 = tanhf(a + pre0 + b_agg[tid]);
  float e1m = 0.25f * (E1C[n0 * DD + tid] + E1C[n1 * DD + tid] + E1C[n2 * DD + tid] + E1C[n3 * DD + tid]);
  s_b[tid] = e1m + e0;
  __syncthreads();
  a = 0.f;
#pragma unroll 8
  for (int j = 0; j < DD; ++j) a += WtA0[j * DD + tid] * s_b[j];
  s_c[tid] = tanhf(a + b_agg[tid]);
  __syncthreads();
  a = 0.f;
#pragma unroll 8
  for (int j = 0; j < DD; ++j) a += WtAL[j * DD + tid] * s_c[j];
  float aggv = tanhf(a + b_agg_last[tid]);
  __syncthreads();
  s_b[tid] = s_qrm[2] ? aggv : s_a[tid];
  __syncthreads();
  const float* ErI = ws + OFF_ERIH1 + s_qrm[1] * 384;
  float g0 = 0.f, g1 = 0.f, g2a = 0.f;
#pragma unroll 4
  for (int j = 0; j < DD; ++j) {
    float x = s_b[j];
    g0 += WtIH1A[j * 384 + tid] * x;
    g1 += WtIH1A[j * 384 + 128 + tid] * x;
    g2a += WtIH1A[j * 384 + 256 + tid] * x;
  }
  float* gi1 = ws + OFF_GI1 + (size_t)bt * 384;
  gi1[tid] = g0 + ErI[tid] + b_ih1[tid];
  gi1[128 + tid] = g1 + ErI[128 + tid] + b_ih1[128 + tid];
  gi1[256 + tid] = g2a + ErI[256 + tid] + b_ih1[256 + tid];
}

// ---------------- K2: per-(b,t) scores + top-10 + cid ----------------
__global__ __launch_bounds__(128) void k_topk(
    const int* __restrict__ qseq, const int* __restrict__ qctab,
    const float* __restrict__ Eq, float* __restrict__ ws) {
  int* tix = (int*)(ws + OFF_TIX);
  int* tmsk = (int*)(ws + OFF_TMSK);
  int* cid = (int*)(ws + OFF_CID);
  int bt = blockIdx.x;
  int b = bt / TST, t = bt - b * TST;
  int tid = threadIdx.x;
  int lane = tid & 63, wv = tid >> 6;
  __shared__ float s_e[DD];
  __shared__ float s_sc[SEQL];
  __shared__ float s_wv[2];
  __shared__ int s_wi[2];
  int qn = qseq[b * SEQL + t + 1];
  s_e[tid] = Eq[(size_t)qn * DD + tid];
  if (tid < 5) cid[bt * 5 + tid] = (tid == 0) ? qn : qctab[qn * NQCC + tid - 1];
  __syncthreads();
  float sc = NEGV;
  if (tid < t) {
    int qs = qseq[b * SEQL + tid];
    float a = 0.f;
#pragma unroll 8
    for (int j = 0; j < DD; ++j) a += Eq[(size_t)qs * DD + j] * s_e[j];
    sc = a;
  }
  s_sc[tid] = sc;
  __syncthreads();
  for (int k = 0; k < RKK; ++k) {
    float v = s_sc[tid];
    int ix = tid;
    for (int off = 32; off > 0; off >>= 1) {
      float ov = __shfl_down(v, off);
      int oi = __shfl_down(ix, off);
      if (ov > v || (ov == v && oi < ix)) { v = ov; ix = oi; }
    }
    if (lane == 0) { s_wv[wv] = v; s_wi[wv] = ix; }
    __syncthreads();
    if (tid == 0) {
      float v0 = s_wv[0], v1 = s_wv[1];
      int i0 = s_wi[0], i1 = s_wi[1];
      if (v1 > v0 || (v1 == v0 && i1 < i0)) { v0 = v1; i0 = i1; }
      tix[bt * RKK + k] = i0;
      tmsk[bt * RKK + k] = (v0 > NEGV * 0.5f) ? 1 : 0;
      s_sc[i0] = -__builtin_inff();
    }
    __syncthreads();
  }
}

// ---------------- K3: sequential scan, register-resident weights ----------------
__global__ __launch_bounds__(512, 2) void k_seq(
    const float* __restrict__ Eq, const float* __restrict__ Ec,
    const float* __restrict__ b_hh1, const float* __restrict__ b_ih2,
    const float* __restrict__ b_hh2, const float* __restrict__ bq,
    const float* __restrict__ bk, const float* __restrict__ Ww,
    const float* __restrict__ bw, const float* __restrict__ h1i,
    const float* __restrict__ h2i, float* __restrict__ ws,
    float* __restrict__ out) {
  const int tid = threadIdx.x;
  const int b = blockIdx.x;
  const int i = tid & 127, jc = tid >> 7;
  const int lane = tid & 63, wv = tid >> 6;
  const int bt0 = b * TST;

  const float* gi1_all = ws + OFF_GI1;
  const int* tix_all = (const int*)(ws + OFF_TIX);
  const int* tmsk_all = (const int*)(ws + OFF_TMSK);
  const int* cid_all = (const int*)(ws + OFF_CID);
  const uint4* wp = (const uint4*)((const unsigned*)ws + OFF_WPACK);

  __shared__ float s_h1[DD], s_h2[DD], s_h1n[DD], s_g2[DD], s_Qpg2[DD];
  __shared__ float s_part[6][4][DD];
  __shared__ unsigned short qph[SEQL * DD];  // bf16 Qp-cache of state_hist rows
  __shared__ float s_qc[5][DD];
  __shared__ float s_gi1[384];
  __shared__ float s_Kp[5][DD];
  __shared__ float s_vhh[SEQL];
  __shared__ float s_logit[64];
  __shared__ float s_bhh1[384], s_bih2[384], s_bhh2[384], s_bq[DD], s_bk[DD];
  __shared__ float s_vh[11], s_vqc[5], s_bw;
  __shared__ int s_tix[RKK], s_hm[11], s_cidn[5];

  // --- weights -> registers (bf16 packed: 11 chunks x 4 uint4 = 176 VGPR) ---
  uint4 wgt[11][4];
#pragma unroll
  for (int c = 0; c < 11; ++c)
#pragma unroll
    for (int kk = 0; kk < 4; ++kk)
      wgt[c][kk] = wp[((c * 4 + jc) * 4 + kk) * 128 + i];

  // --- prologue ---
  for (int o = tid; o < 384; o += 512) { s_bhh1[o] = b_hh1[o]; s_bih2[o] = b_ih2[o]; s_bhh2[o] = b_hh2[o]; }
  if (tid < 128) { s_bq[tid] = bq[tid]; s_bk[tid] = bk[tid]; s_h1[tid] = h1i[b * DD + tid]; s_h2[tid] = h2i[b * DD + tid]; s_vhh[tid] = 0.f; }
  float wh_lo = 0.f, wh_hi = 0.f, wqc_lo = 0.f, wqc_hi = 0.f;
  if (wv == 7) { wh_lo = Ww[lane]; wh_hi = Ww[64 + lane]; wqc_lo = Ww[128 + lane]; wqc_hi = Ww[192 + lane]; }
  if (tid == 0) { s_bw = bw[0]; out[b * SEQL + 1] = 0.f; s_hm[0] = 1; }
  if (tid >= 8 && tid < 13) s_cidn[tid - 8] = cid_all[bt0 * 5 + tid - 8];
  if (tid >= 16 && tid < 26) s_tix[tid - 16] = tix_all[bt0 * RKK + tid - 16];
  if (tid >= 32 && tid < 42) s_hm[1 + tid - 32] = tmsk_all[bt0 * RKK + tid - 32];
  __syncthreads();
  for (int o = tid; o < SEQL * DD; o += 512) qph[o] = f2b(s_bq[o & 127]);
  if (tid < 96) ((float4*)s_gi1)[tid] = ((const float4*)(gi1_all + (size_t)bt0 * 384))[tid];
  else if (tid < 256) {
    int s = (tid - 96) >> 5, p = (tid - 96) & 31;
    const float* src = s ? (Ec + (size_t)s_cidn[s] * DD) : (Eq + (size_t)s_cidn[0] * DD);
    ((float4*)s_qc[s])[p] = ((const float4*)src)[p];
  }
  __syncthreads();
  if (tid < 5) s_cidn[tid] = cid_all[(bt0 + 1) * 5 + tid];
  __syncthreads();

  for (int t = 0; t < TST; ++t) {
    const int tpn = (t + 1 < TST) ? t + 1 : TST - 1;
    const int tpp = (t + 2 < TST) ? t + 2 : TST - 1;
    float4 pf = {0.f, 0.f, 0.f, 0.f};
    int pfs = 0;

    // ---- Phase A: prefetch issue + gh1 partials ----
    if (tid < 96) pf = ((const float4*)(gi1_all + (size_t)(bt0 + tpn) * 384))[tid];
    else if (tid < 256) {
      int s = (tid - 96) >> 5, p = (tid - 96) & 31;
      const float* src = s ? (Ec + (size_t)s_cidn[s] * DD) : (Eq + (size_t)s_cidn[0] * DD);
      pf = ((const float4*)src)[p];
    } else if (tid >= 384 && tid < 409) {
      int k = tid - 384;
      if (k < 10) pfs = tix_all[(bt0 + tpn) * RKK + k];
      else if (k < 20) pfs = tmsk_all[(bt0 + tpn) * RKK + k - 10];
      else pfs = cid_all[(bt0 + tpp) * 5 + k - 20];
    }
    {
      const float4* xp = (const float4*)s_h1 + (jc << 3);
      float a0 = 0.f, a1 = 0.f, a2 = 0.f;
#pragma unroll
      for (int kk = 0; kk < 4; ++kk) {
        float4 x0 = xp[2 * kk], x1 = xp[2 * kk + 1];
        a0 = dot8(a0, wgt[0][kk], x0, x1);
        a1 = dot8(a1, wgt[1][kk], x0, x1);
        a2 = dot8(a2, wgt[2][kk], x0, x1);
      }
      s_part[0][jc][i] = a0; s_part[1][jc][i] = a1; s_part[2][jc][i] = a2;
    }
    __syncthreads();

    // ---- Phase B: GRU1 combine ; wave7: vqc dots ----
    if (tid < 128) {
      float gr = s_part[0][0][i] + s_part[0][1][i] + s_part[0][2][i] + s_part[0][3][i] + s_bhh1[i];
      float gz = s_part[1][0][i] + s_part[1][1][i] + s_part[1][2][i] + s_part[1][3][i] + s_bhh1[128 + i];
      float gn = s_part[2][0][i] + s_part[2][1][i] + s_part[2][2][i] + s_part[2][3][i] + s_bhh1[256 + i];
      float r = sigm(s_gi1[i] + gr);
      float z = sigm(s_gi1[128 + i] + gz);
      float n = tanhf(s_gi1[256 + i] + r * gn);
      s_h1n[i] = (1.f - z) * n + z * s_h1[i];
    } else if (wv == 7) {
#pragma unroll
      for (int s = 0; s < 5; ++s) {
        float pa = s_qc[s][lane] * wqc_lo + s_qc[s][64 + lane] * wqc_hi;
        for (int off = 32; off > 0; off >>= 1) pa += __shfl_down(pa, off);
        if (lane == 0) s_vqc[s] = pa;
      }
    }
    __syncthreads();

    // ---- Phase C: gi2 + gh2 partials ----
    {
      const float4* xn = (const float4*)s_h1n + (jc << 3);
      const float4* xh = (const float4*)s_h2 + (jc << 3);
      float a0 = 0.f, a1 = 0.f, a2 = 0.f, c0 = 0.f, c1 = 0.f, c2 = 0.f;
#pragma unroll
      for (int kk = 0; kk < 4; ++kk) {
        float4 n0 = xn[2 * kk], n1 = xn[2 * kk + 1];
        float4 h0 = xh[2 * kk], h1v = xh[2 * kk + 1];
        a0 = dot8(a0, wgt[3][kk], n0, n1);
        a1 = dot8(a1, wgt[4][kk], n0, n1);
        a2 = dot8(a2, wgt[5][kk], n0, n1);
        c0 = dot8(c0, wgt[6][kk], h0, h1v);
        c1 = dot8(c1, wgt[7][kk], h0, h1v);
        c2 = dot8(c2, wgt[8][kk], h0, h1v);
      }
      s_part[0][jc][i] = a0; s_part[1][jc][i] = a1; s_part[2][jc][i] = a2;
      s_part[3][jc][i] = c0; s_part[4][jc][i] = c1; s_part[5][jc][i] = c2;
    }
    __syncthreads();

    // ---- Phase D: GRU2 combine -> g2 ----
    if (tid < 128) {
      float gir = s_part[0][0][i] + s_part[0][1][i] + s_part[0][2][i] + s_part[0][3][i] + s_bih2[i];
      float giz = s_part[1][0][i] + s_part[1][1][i] + s_part[1][2][i] + s_part[1][3][i] + s_bih2[128 + i];
      float gin = s_part[2][0][i] + s_part[2][1][i] + s_part[2][2][i] + s_part[2][3][i] + s_bih2[256 + i];
      float ghr = s_part[3][0][i] + s_part[3][1][i] + s_part[3][2][i] + s_part[3][3][i] + s_bhh2[i];
      float ghz = s_part[4][0][i] + s_part[4][1][i] + s_part[4][2][i] + s_part[4][3][i] + s_bhh2[128 + i];
      float ghn = s_part[5][0][i] + s_part[5][1][i] + s_part[5][2][i] + s_part[5][3][i] + s_bhh2[256 + i];
      float r = sigm(gir + ghr), z = sigm(giz + ghz), n = tanhf(gin + r * ghn);
      s_g2[i] = (1.f - z) * n + z * s_h2[i];
    }
    __syncthreads();

    // ---- Phase E: Qp + 5x Kp partials ----
    {
      const float4* xg = (const float4*)s_g2 + (jc << 3);
      const float4* q0p = (const float4*)s_qc[0] + (jc << 3);
      const float4* q1p = (const float4*)s_qc[1] + (jc << 3);
      const float4* q2p = (const float4*)s_qc[2] + (jc << 3);
      const float4* q3p = (const float4*)s_qc[3] + (jc << 3);
      const float4* q4p = (const float4*)s_qc[4] + (jc << 3);
      float aq = 0.f, k0 = 0.f, k1 = 0.f, k2 = 0.f, k3 = 0.f, k4 = 0.f;
#pragma unroll
      for (int kk = 0; kk < 4; ++kk) {
        float4 g0 = xg[2 * kk], g1 = xg[2 * kk + 1];
        aq = dot8(aq, wgt[9][kk], g0, g1);
        uint4 wk_ = wgt[10][kk];
        float w0 = bl(wk_.x), w1 = bh(wk_.x), w2 = bl(wk_.y), w3 = bh(wk_.y);
        float w4 = bl(wk_.z), w5 = bh(wk_.z), w6 = bl(wk_.w), w7 = bh(wk_.w);
        float4 a0, a1;
        a0 = q0p[2 * kk]; a1 = q0p[2 * kk + 1];
        k0 = fmaf(w0, a0.x, fmaf(w1, a0.y, fmaf(w2, a0.z, fmaf(w3, a0.w, fmaf(w4, a1.x, fmaf(w5, a1.y, fmaf(w6, a1.z, fmaf(w7, a1.w, k0))))))));
        a0 = q1p[2 * kk]; a1 = q1p[2 * kk + 1];
        k1 = fmaf(w0, a0.x, fmaf(w1, a0.y, fmaf(w2, a0.z, fmaf(w3, a0.w, fmaf(w4, a1.x, fmaf(w5, a1.y, fmaf(w6, a1.z, fmaf(w7, a1.w, k1))))))));
        a0 = q2p[2 * kk]; a1 = q2p[2 * kk + 1];
        k2 = fmaf(w0, a0.x, fmaf(w1, a0.y, fmaf(w2, a0.z, fmaf(w3, a0.w, fmaf(w4, a1.x, fmaf(w5, a1.y, fmaf(w6, a1.z, fmaf(w7, a1.w, k2))))))));
        a0 = q3p[2 * kk]; a1 = q3p[2 * kk + 1];
        k3 = fmaf(w0, a0.x, fmaf(w1, a0.y, fmaf(w2, a0.z, fmaf(w3, a0.w, fmaf(w4, a1.x, fmaf(w5, a1.y, fmaf(w6, a1.z, fmaf(w7, a1.w, k3))))))));
        a0 = q4p[2 * kk]; a1 = q4p[2 * kk + 1];
        k4 = fmaf(w0, a0.x, fmaf(w1, a0.y, fmaf(w2, a0.z, fmaf(w3, a0.w, fmaf(w4, a1.x, fmaf(w5, a1.y, fmaf(w6, a1.z, fmaf(w7, a1.w, k4))))))));
      }
      s_part[0][jc][i] = aq; s_part[1][jc][i] = k0; s_part[2][jc][i] = k1;
      s_part[3][jc][i] = k2; s_part[4][jc][i] = k3; s_part[5][jc][i] = k4;
    }
    __syncthreads();

    // ---- Phase F: reduces (Qp, Kp) + vh + gathers ----
    if (tid < 128) {
      s_Qpg2[i] = s_part[0][0][i] + s_part[0][1][i] + s_part[0][2][i] + s_part[0][3][i] + s_bq[i];
    } else if (tid < 448) {
      for (int o = tid - 128; o < 640; o += 320) {
        int s = o >> 7, ii = o & 127;
        s_Kp[s][ii] = s_part[1 + s][0][ii] + s_part[1 + s][1][ii] + s_part[1 + s][2][ii] + s_part[1 + s][3][ii] + s_bk[ii];
      }
    } else {
      float pa = s_g2[lane] * wh_lo + s_g2[64 + lane] * wh_hi;
      for (int off = 32; off > 0; off >>= 1) pa += __shfl_down(pa, off);
      if (lane == 0) s_vh[0] = pa;
      if (lane >= 16 && lane < 26) s_vh[1 + lane - 16] = s_vhh[s_tix[lane - 16]];
    }
    __syncthreads();

    // ---- Phase G: 55 logits ----
    if (tid < 440) {
      int p = tid >> 3, sub = tid & 7;
      int q = p / 5, s = p - q * 5;
      const float* kp = s_Kp[s] + sub * 16;
      float a = 0.f;
      if (q == 0) {
        const float* qp = s_Qpg2 + sub * 16;
#pragma unroll
        for (int k = 0; k < 16; ++k) a = fmaf(qp[k], kp[k], a);
      } else {
        const unsigned* rp = (const unsigned*)(qph + (s_tix[q - 1] << 7) + (sub << 4));
#pragma unroll
        for (int k = 0; k < 8; ++k) {
          unsigned u = rp[k];
          a = fmaf(bl(u), kp[2 * k], a);
          a = fmaf(bh(u), kp[2 * k + 1], a);
        }
      }
      a += __shfl_down(a, 4);
      a += __shfl_down(a, 2);
      a += __shfl_down(a, 1);
      if (sub == 0) s_logit[p] = s_hm[q] ? a : NEGV;
    } else if (tid < 449) {
      s_logit[55 + tid - 440] = NEGV;
    }
    __syncthreads();

    // ---- Phase H: softmax+out (wave7) ; commits ; prefetch LDS writes ----
    if (wv == 7) {
      float l = s_logit[lane];
      float m = l;
      for (int off = 32; off > 0; off >>= 1) m = fmaxf(m, __shfl_xor(m, off));
      float e = __expf(l - m);
      float v = 0.f;
      if (lane < 55) {
        int q = lane / 5, s = lane - q * 5;
        v = sigm(s_vh[q] + s_vqc[s] + s_bw);
      }
      float num = e * v, den = e;
      for (int off = 32; off > 0; off >>= 1) { num += __shfl_xor(num, off); den += __shfl_xor(den, off); }
      if (lane == 0) out[b * SEQL + ((t == 0) ? 0 : (t + 1))] = num / den;
    } else if (tid < 96) {
      ((float4*)s_gi1)[tid] = pf;
    } else if (tid < 256) {
      int s = (tid - 96) >> 5, p = (tid - 96) & 31;
      ((float4*)s_qc[s])[p] = pf;
    } else if (tid < 384) {
      int ii = tid - 256;
      s_h1[ii] = s_h1n[ii];
      if (t > 0) {
        s_h2[ii] = s_g2[ii];
        qph[t * DD + ii] = f2b(s_Qpg2[ii]);
        if (ii == 0) s_vhh[t] = s_vh[0];
      }
    } else if (tid < 409) {
      int k = tid - 384;
      if (k < 10) s_tix[k] = pfs;
      else if (k < 20) s_hm[1 + k - 10] = pfs;
      else s_cidn[k - 20] = pfs;
    }
    __syncthreads();
  }
}

extern "C" void kernel_launch(void* const* d_in, const int* in_sizes, int n_in,
                              void* d_out, int out_size, void* d_ws, size_t ws_size,
                              hipStream_t stream) {
  (void)in_sizes; (void)n_in; (void)out_size; (void)ws_size;
  const int* qseq = (const int*)d_in[0];
  const int* rseq = (const int*)d_in[1];
  const int* mseq = (const int*)d_in[2];
  const int* qnbr = (const int*)d_in[3];
  const int* cnbr = (const int*)d_in[4];
  const int* qctab = (const int*)d_in[5];
  const float* Eq = (const float*)d_in[6];
  const float* Ec = (const float*)d_in[7];
  const float* Er = (const float*)d_in[8];
  const float* W_ih1 = (const float*)d_in[9];
  const float* W_hh1 = (const float*)d_in[10];
  const float* b_ih1 = (const float*)d_in[11];
  const float* b_hh1 = (const float*)d_in[12];
  const float* W_ih2 = (const float*)d_in[13];
  const float* W_hh2 = (const float*)d_in[14];
  const float* b_ih2 = (const float*)d_in[15];
  const float* b_hh2 = (const float*)d_in[16];
  const float* W_agg = (const float*)d_in[17];
  const float* b_agg = (const float*)d_in[18];
  const float* W_agg_last = (const float*)d_in[19];
  const float* b_agg_last = (const float*)d_in[20];
  const float* Wq = (const float*)d_in[21];
  const float* bq = (const float*)d_in[22];
  const float* Wk = (const float*)d_in[23];
  const float* bk = (const float*)d_in[24];
  const float* Ww = (const float*)d_in[25];
  const float* bw = (const float*)d_in[26];
  const float* h1i = (const float*)d_in[27];
  const float* h2i = (const float*)d_in[28];
  float* ws = (float*)d_ws;
  float* out = (float*)d_out;

  hipLaunchKernelGGL(k_prep, dim3(740), dim3(256), 0, stream,
                     W_hh1, W_ih2, W_hh2, Wq, Wk, W_agg, W_agg_last, W_ih1, Er, ws);
  hipLaunchKernelGGL(k_concept, dim3(1000), dim3(128), 0, stream,
                     cnbr, Eq, Ec, b_agg, ws);
  hipLaunchKernelGGL(k_agg, dim3(BSZ * TST), dim3(128), 0, stream,
                     qseq, rseq, mseq, qnbr, Eq, b_agg, b_agg_last, b_ih1, ws);
  hipLaunchKernelGGL(k_topk, dim3(BSZ * TST), dim3(128), 0, stream,
                     qseq, qctab, Eq, ws);
  hipLaunchKernelGGL(k_seq, dim3(BSZ), dim3(512), 0, stream,
                     Eq, Ec, b_hh1, b_ih2, b_hh2, bq, bk, Ww, bw,
                     h1i, h2i, ws, out);
}

// Round 4
// 874.074 us; speedup vs baseline: 7.5740x; 7.5740x over previous
//
#include <hip/hip_runtime.h>

#define DD 128
#define BSZ 128
#define SEQL 128
#define TST 127
#define QNN 4
#define CNN 10
#define NQCC 4
#define RKK 10
#define NEGV -1000000000.0f

// ---- workspace float offsets ----
#define OFF_WTA0    0         // [128][128] W_agg0^T
#define OFF_WTA1    16384     // [128][128] W_agg1^T
#define OFF_WTAL    32768     // [128][128] W_agg_last^T
#define OFF_WTIH1A  49152     // [128][384] W_ih1[:, :128]^T
#define OFF_ERIH1   98304     // [2][384]   W_ih1[:,128:]@Er[r]
#define OFF_WKT     99072     // [128][128] Wk^T
#define OFF_WPACK   115456    // 81920 uints: f16-pair packed W_hh1,W_ih2,W_hh2,Wq
#define OFF_ECA0    197376    // [1000][128] W_agg0 @ Ec[c]
#define OFF_E1C     325376    // [1000][128] tanh(W_agg1@(cmean+Ec)+b1)
#define OFF_KPC     453376    // [1000][64] uints (f16 pairs of Wk@Ec+bk)
#define OFF_VQCC    517376    // [1000] f32 dot(Wqc, Ec[c])
#define OFF_GI1     518400    // [16256][384]
#define OFF_KP0     6760704   // [16256][64] uints (f16 pairs of Wk@Eq[qnext]+bk)
#define OFF_VQC0    7801088   // [16256] f32
#define OFF_TIX     7817344   // [16256][10] int
#define OFF_TMSK    7979904   // [16256][10] int
#define OFF_CID     8142464   // [16256][5] int

typedef __fp16 h2 __attribute__((ext_vector_type(2)));

__device__ __forceinline__ float sigm(float x) { return 1.0f / (1.0f + __expf(-x)); }
__device__ __forceinline__ unsigned pkh(float a, float b) {
  h2 v; v.x = (__fp16)a; v.y = (__fp16)b;   // RNE converts
  return __builtin_bit_cast(unsigned, v);
}
__device__ __forceinline__ float fd2(float acc, unsigned w, h2 x) {
  return __builtin_amdgcn_fdot2(__builtin_bit_cast(h2, w), x, acc, false);
}
__device__ __forceinline__ float fd2u(float acc, unsigned w, unsigned x) {
  return __builtin_amdgcn_fdot2(__builtin_bit_cast(h2, w), __builtin_bit_cast(h2, x), acc, false);
}

// ---------------- K0a: fp32 tables + f16 packed weight table ----------------
__global__ __launch_bounds__(256) void k_prep(
    const float* __restrict__ W_hh1, const float* __restrict__ W_ih2,
    const float* __restrict__ W_hh2, const float* __restrict__ Wq,
    const float* __restrict__ Wk, const float* __restrict__ W_agg,
    const float* __restrict__ W_agg_last, const float* __restrict__ W_ih1,
    const float* __restrict__ Er, float* __restrict__ ws) {
  int idx = blockIdx.x * 256 + threadIdx.x;
  const int TOT = 197376;
  for (int o = idx; o < TOT; o += gridDim.x * 256) {
    int r = o;
    if (r < 16384) { int j = r >> 7, i = r & 127; ws[OFF_WTA0 + r] = W_agg[i * 128 + j]; continue; }
    r -= 16384;
    if (r < 16384) { int j = r >> 7, i = r & 127; ws[OFF_WTA1 + r] = W_agg[16384 + i * 128 + j]; continue; }
    r -= 16384;
    if (r < 16384) { int j = r >> 7, i = r & 127; ws[OFF_WTAL + r] = W_agg_last[i * 128 + j]; continue; }
    r -= 16384;
    if (r < 49152) { int j = r / 384, i = r % 384; ws[OFF_WTIH1A + r] = W_ih1[i * 256 + j]; continue; }
    r -= 49152;
    if (r < 768) {
      int rr = r / 384, i2 = r % 384;
      float a = 0.f;
      for (int j = 0; j < 128; ++j) a += Er[rr * 128 + j] * W_ih1[i2 * 256 + 128 + j];
      ws[OFF_ERIH1 + r] = a; continue;
    }
    r -= 768;
    if (r < 16384) { int j = r >> 7, i = r & 127; ws[OFF_WKT + r] = Wk[i * 128 + j]; continue; }
    r -= 16384;
    { // WPACK: r in [0, 81920)
      int n = r & 3; int q = r >> 2;
      int i = q & 127; q >>= 7;
      int kk = q & 3; q >>= 2;
      int jc = q & 3; int c = q >> 2;
      int j0 = jc * 32 + kk * 8 + n * 2;
      const float* row;
      if (c < 3) row = W_hh1 + (size_t)(c * 128 + i) * 128;
      else if (c < 6) row = W_ih2 + (size_t)((c - 3) * 128 + i) * 128;
      else if (c < 9) row = W_hh2 + (size_t)((c - 6) * 128 + i) * 128;
      else row = Wq + (size_t)i * 128;
      ((unsigned*)ws)[OFF_WPACK + r] = pkh(row[j0], row[j0 + 1]);
    }
  }
}

// ---------------- K0b: per-concept tables (+KpC, vqcC) ----------------
__global__ __launch_bounds__(128) void k_concept(
    const int* __restrict__ cnbr, const float* __restrict__ Eq,
    const float* __restrict__ Ec, const float* __restrict__ b_agg,
    const float* __restrict__ bk, const float* __restrict__ Ww,
    float* __restrict__ ws) {
  int c = blockIdx.x;
  int tid = threadIdx.x;
  __shared__ int s_nb[CNN];
  __shared__ float s_v[DD], s_ec[DD], s_t2[DD], s_w2[DD];
  if (tid < CNN) s_nb[tid] = cnbr[c * CNN + tid];
  __syncthreads();
  float ec = Ec[c * DD + tid];
  float cm = 0.f;
#pragma unroll
  for (int l = 0; l < CNN; ++l) cm += Eq[(size_t)s_nb[l] * DD + tid];
  s_ec[tid] = ec;
  s_v[tid] = cm * 0.1f + ec;
  __syncthreads();
  const float* WtA0 = ws + OFF_WTA0;
  const float* WtA1 = ws + OFF_WTA1;
  const float* WkT = ws + OFF_WKT;
  float a1 = 0.f, a0 = 0.f, kc = 0.f;
#pragma unroll 8
  for (int j = 0; j < DD; ++j) {
    a1 += WtA1[j * DD + tid] * s_v[j];
    a0 += WtA0[j * DD + tid] * s_ec[j];
    kc += WkT[j * DD + tid] * s_ec[j];
  }
  ws[OFF_E1C + c * DD + tid] = tanhf(a1 + b_agg[DD + tid]);
  ws[OFF_ECA0 + c * DD + tid] = a0;
  s_t2[tid] = kc + bk[tid];
  s_w2[tid] = s_ec[tid] * Ww[128 + tid];
  __syncthreads();
  if (tid < 64) {
    ((unsigned*)ws)[OFF_KPC + c * 64 + tid] = pkh(s_t2[2 * tid], s_t2[2 * tid + 1]);
    float pa = s_w2[tid] + s_w2[tid + 64];
    for (int off = 32; off > 0; off >>= 1) pa += __shfl_down(pa, off);
    if (tid == 0) ws[OFF_VQCC + c] = pa;
  }
}

// ---------------- K0c: per-(b,t) aggregation + gi1 ----------------
__global__ __launch_bounds__(128) void k_agg(
    const int* __restrict__ qseq, const int* __restrict__ rseq,
    const int* __restrict__ mseq, const int* __restrict__ qnbr,
    const float* __restrict__ Eq, const float* __restrict__ b_agg,
    const float* __restrict__ b_agg_last, const float* __restrict__ b_ih1,
    float* __restrict__ ws) {
  int bt = blockIdx.x;
  int b = bt / TST, t = bt - b * TST;
  int tid = threadIdx.x;
  __shared__ int s_n1[QNN];
  __shared__ int s_qrm[3];
  __shared__ float s_a[DD], s_b[DD], s_c[DD];
  if (tid < 3) s_qrm[tid] = (tid == 0) ? qseq[b * SEQL + t] : (tid == 1 ? rseq[b * SEQL + t] : mseq[b * SEQL + t]);
  __syncthreads();
  int q = s_qrm[0];
  if (tid < QNN) s_n1[tid] = qnbr[q * QNN + tid];
  s_a[tid] = Eq[(size_t)q * DD + tid];
  __syncthreads();
  const float* WtA0 = ws + OFF_WTA0;
  const float* WtAL = ws + OFF_WTAL;
  const float* WtIH1A = ws + OFF_WTIH1A;
  const float* EcA0 = ws + OFF_ECA0;
  const float* E1C = ws + OFF_E1C;
  float a = 0.f;
#pragma unroll 8
  for (int j = 0; j < DD; ++j) a += WtA0[j * DD + tid] * s_a[j];
  int n0 = s_n1[0], n1 = s_n1[1], n2 = s_n1[2], n3 = s_n1[3];
  float pre0 = 0.25f * (EcA0[n0 * DD + tid] + EcA0[n1 * DD + tid] + EcA0[n2 * DD + tid] + EcA0[n3 * DD + tid]);
  float e0 = tanhf(a + pre0 + b_agg[tid]);
  float e1m = 0.25f * (E1C[n0 * DD + tid] + E1C[n1 * DD + tid] + E1C[n2 * DD + tid] + E1C[n3 * DD + tid]);
  s_b[tid] = e1m + e0;
  __syncthreads();
  a = 0.f;
#pragma unroll 8
  for (int j = 0; j < DD; ++j) a += WtA0[j * DD + tid] * s_b[j];
  s_c[tid] = tanhf(a + b_agg[tid]);
  __syncthreads();
  a = 0.f;
#pragma unroll 8
  for (int j = 0; j < DD; ++j) a += WtAL[j * DD + tid] * s_c[j];
  float aggv = tanhf(a + b_agg_last[tid]);
  __syncthreads();
  s_b[tid] = s_qrm[2] ? aggv : s_a[tid];
  __syncthreads();
  const float* ErI = ws + OFF_ERIH1 + s_qrm[1] * 384;
  float g0 = 0.f, g1 = 0.f, g2a = 0.f;
#pragma unroll 4
  for (int j = 0; j < DD; ++j) {
    float x = s_b[j];
    g0 += WtIH1A[j * 384 + tid] * x;
    g1 += WtIH1A[j * 384 + 128 + tid] * x;
    g2a += WtIH1A[j * 384 + 256 + tid] * x;
  }
  float* gi1 = ws + OFF_GI1 + (size_t)bt * 384;
  gi1[tid] = g0 + ErI[tid] + b_ih1[tid];
  gi1[128 + tid] = g1 + ErI[128 + tid] + b_ih1[128 + tid];
  gi1[256 + tid] = g2a + ErI[256 + tid] + b_ih1[256 + tid];
}

// ---------------- K2: scores + top-10 + cid + Kp0 + vqc0 ----------------
__global__ __launch_bounds__(128) void k_topk(
    const int* __restrict__ qseq, const int* __restrict__ qctab,
    const float* __restrict__ Eq, const float* __restrict__ bk,
    const float* __restrict__ Ww, float* __restrict__ ws) {
  int* tix = (int*)(ws + OFF_TIX);
  int* tmsk = (int*)(ws + OFF_TMSK);
  int* cid = (int*)(ws + OFF_CID);
  int bt = blockIdx.x;
  int b = bt / TST, t = bt - b * TST;
  int tid = threadIdx.x;
  int lane = tid & 63, wv = tid >> 6;
  __shared__ float s_e[DD];
  __shared__ float s_sc[SEQL];
  __shared__ float s_w2[DD];
  __shared__ float s_wv[2];
  __shared__ int s_wi[2];
  int qn = qseq[b * SEQL + t + 1];
  s_e[tid] = Eq[(size_t)qn * DD + tid];
  if (tid < 5) cid[bt * 5 + tid] = (tid == 0) ? qn : qctab[qn * NQCC + tid - 1];
  __syncthreads();
  float sc = NEGV;
  if (tid < t) {
    int qs = qseq[b * SEQL + tid];
    float a = 0.f;
#pragma unroll 8
    for (int j = 0; j < DD; ++j) a += Eq[(size_t)qs * DD + j] * s_e[j];
    sc = a;
  }
  s_sc[tid] = sc;
  __syncthreads();
  for (int k = 0; k < RKK; ++k) {
    float v = s_sc[tid];
    int ix = tid;
    for (int off = 32; off > 0; off >>= 1) {
      float ov = __shfl_down(v, off);
      int oi = __shfl_down(ix, off);
      if (ov > v || (ov == v && oi < ix)) { v = ov; ix = oi; }
    }
    if (lane == 0) { s_wv[wv] = v; s_wi[wv] = ix; }
    __syncthreads();
    if (tid == 0) {
      float v0 = s_wv[0], v1 = s_wv[1];
      int i0 = s_wi[0], i1 = s_wi[1];
      if (v1 > v0 || (v1 == v0 && i1 < i0)) { v0 = v1; i0 = i1; }
      tix[bt * RKK + k] = i0;
      tmsk[bt * RKK + k] = (v0 > NEGV * 0.5f) ? 1 : 0;
      s_sc[i0] = -__builtin_inff();
    }
    __syncthreads();
  }
  // Kp0 = Wk@Eq[qn] + bk (f16-pair packed), vqc0 = dot(Wqc, Eq[qn])
  const float* WkT = ws + OFF_WKT;
  float kc = 0.f;
#pragma unroll 8
  for (int j = 0; j < DD; ++j) kc += WkT[j * DD + tid] * s_e[j];
  s_sc[tid] = kc + bk[tid];
  s_w2[tid] = s_e[tid] * Ww[128 + tid];
  __syncthreads();
  if (tid < 64) {
    ((unsigned*)ws)[OFF_KP0 + bt * 64 + tid] = pkh(s_sc[2 * tid], s_sc[2 * tid + 1]);
    float pa = s_w2[tid] + s_w2[tid + 64];
    for (int off = 32; off > 0; off >>= 1) pa += __shfl_down(pa, off);
    if (tid == 0) ws[OFF_VQC0 + bt] = pa;
  }
}

// ---------------- K3: sequential scan, f16 register-resident weights ----------------
__global__ __launch_bounds__(512, 2) void k_seq(
    const float* __restrict__ b_hh1, const float* __restrict__ b_ih2,
    const float* __restrict__ b_hh2, const float* __restrict__ bq,
    const float* __restrict__ Ww, const float* __restrict__ bw,
    const float* __restrict__ h1i, const float* __restrict__ h2i,
    float* __restrict__ ws, float* __restrict__ out) {
  const int tid = threadIdx.x;
  const int b = blockIdx.x;
  const int i = tid & 127, jc = tid >> 7;
  const int lane = tid & 63, wv = tid >> 6;
  const int bt0 = b * TST;

  const float4* gi1f4 = (const float4*)(ws + OFF_GI1);
  const unsigned* Kp0pk = (const unsigned*)ws + OFF_KP0;
  const unsigned* KpCpk = (const unsigned*)ws + OFF_KPC;
  const float* vqc0_all = ws + OFF_VQC0;
  const float* vqcC_all = ws + OFF_VQCC;
  const int* tix_all = (const int*)(ws + OFF_TIX);
  const int* tmsk_all = (const int*)(ws + OFF_TMSK);
  const int* cid_all = (const int*)(ws + OFF_CID);
  const uint4* wp = (const uint4*)((const unsigned*)ws + OFF_WPACK);

  __shared__ float s_h1[DD], s_h2[DD], s_h1n[DD], s_g2[DD], s_Qpg2[DD];
  __shared__ float s_part[6][4][DD];
  __shared__ unsigned qph_pk[SEQL * 64];  // f16-pair Qp history, XOR(row&63)-swizzled
  __shared__ unsigned s_Kp[5 * 66];       // f16 pairs, stride 66
  __shared__ float s_gi1[384];
  __shared__ float s_vhh[SEQL];
  __shared__ float s_logit[64];
  __shared__ float s_bhh1[384], s_bih2[384], s_bhh2[384], s_bq[DD];
  __shared__ float s_vh[11], s_vqc[2][5], s_bw;
  __shared__ int s_tix[RKK], s_hm[11], s_cidn[5];

  // --- weights -> registers: 10 chunks x 4 uint4 = 160 VGPR ---
  uint4 wgt[10][4];
#pragma unroll
  for (int c = 0; c < 10; ++c)
#pragma unroll
    for (int kk = 0; kk < 4; ++kk)
      wgt[c][kk] = wp[((c * 4 + jc) * 4 + kk) * 128 + i];

  // --- prologue ---
  for (int o = tid; o < 384; o += 512) { s_bhh1[o] = b_hh1[o]; s_bih2[o] = b_ih2[o]; s_bhh2[o] = b_hh2[o]; }
  if (tid < 128) { s_bq[tid] = bq[tid]; s_h1[tid] = h1i[b * DD + tid]; s_h2[tid] = h2i[b * DD + tid]; s_vhh[tid] = 0.f; }
  float wh_lo = 0.f, wh_hi = 0.f;
  if (wv == 7) { wh_lo = Ww[lane]; wh_hi = Ww[64 + lane]; }
  if (tid == 0) { s_bw = bw[0]; out[b * SEQL + 1] = 0.f; s_hm[0] = 1; }
  if (tid >= 8 && tid < 13) s_cidn[tid - 8] = cid_all[bt0 * 5 + tid - 8];
  if (tid >= 16 && tid < 26) s_tix[tid - 16] = tix_all[bt0 * RKK + tid - 16];
  if (tid >= 32 && tid < 42) s_hm[1 + tid - 32] = tmsk_all[bt0 * RKK + tid - 32];
  __syncthreads();
  for (int o = tid; o < SEQL * 64; o += 512) {
    int row = o >> 6, k = o & 63;
    qph_pk[row * 64 + (k ^ (row & 63))] = pkh(s_bq[2 * k], s_bq[2 * k + 1]);
  }
  if (tid < 96) ((float4*)s_gi1)[tid] = gi1f4[(size_t)bt0 * 96 + tid];
  else if (tid < 416) {
    int kx = tid - 96, s = kx >> 6, e = kx & 63;
    s_Kp[s * 66 + e] = (s == 0) ? Kp0pk[(size_t)bt0 * 64 + e] : KpCpk[s_cidn[s] * 64 + e];
  } else if (tid < 421) {
    int s = tid - 416;
    s_vqc[0][s] = (s == 0) ? vqc0_all[bt0] : vqcC_all[s_cidn[s]];
  }
  __syncthreads();
  if (tid < 5) s_cidn[tid] = cid_all[(bt0 + 1) * 5 + tid];
  __syncthreads();

  for (int t = 0; t < TST; ++t) {
    const int par = t & 1, parn = par ^ 1;
    const int tpn = (t + 1 < TST) ? t + 1 : TST - 1;
    const int tpp = (t + 2 < TST) ? t + 2 : TST - 1;
    float4 pf4 = {0.f, 0.f, 0.f, 0.f};
    unsigned pfu = 0; int pfs = 0; float pfv = 0.f;

    // ---- Phase A: prefetch issue + gh1 partials ----
    if (tid < 96) pf4 = gi1f4[(size_t)(bt0 + tpn) * 96 + tid];
    else if (tid < 416) {
      int kx = tid - 96, s = kx >> 6, e = kx & 63;
      pfu = (s == 0) ? Kp0pk[(size_t)(bt0 + tpn) * 64 + e] : KpCpk[s_cidn[s] * 64 + e];
    } else if (tid < 421) {
      int s = tid - 416;
      pfv = (s == 0) ? vqc0_all[bt0 + tpn] : vqcC_all[s_cidn[s]];
    } else if (tid < 431) pfs = tix_all[(bt0 + tpn) * RKK + tid - 421];
    else if (tid < 441) pfs = tmsk_all[(bt0 + tpn) * RKK + tid - 431];
    else if (tid < 446) pfs = cid_all[(bt0 + tpp) * 5 + tid - 441];
    {
      const float4* xp = (const float4*)s_h1 + (jc << 3);
      float a0 = 0.f, a1 = 0.f, a2 = 0.f;
#pragma unroll
      for (int kk = 0; kk < 4; ++kk) {
        float4 x0 = xp[2 * kk], x1 = xp[2 * kk + 1];
        h2 p0 = __builtin_amdgcn_cvt_pkrtz(x0.x, x0.y);
        h2 p1 = __builtin_amdgcn_cvt_pkrtz(x0.z, x0.w);
        h2 p2 = __builtin_amdgcn_cvt_pkrtz(x1.x, x1.y);
        h2 p3 = __builtin_amdgcn_cvt_pkrtz(x1.z, x1.w);
        uint4 w;
        w = wgt[0][kk]; a0 = fd2(a0, w.x, p0); a0 = fd2(a0, w.y, p1); a0 = fd2(a0, w.z, p2); a0 = fd2(a0, w.w, p3);
        w = wgt[1][kk]; a1 = fd2(a1, w.x, p0); a1 = fd2(a1, w.y, p1); a1 = fd2(a1, w.z, p2); a1 = fd2(a1, w.w, p3);
        w = wgt[2][kk]; a2 = fd2(a2, w.x, p0); a2 = fd2(a2, w.y, p1); a2 = fd2(a2, w.z, p2); a2 = fd2(a2, w.w, p3);
      }
      s_part[0][jc][i] = a0; s_part[1][jc][i] = a1; s_part[2][jc][i] = a2;
    }
    __syncthreads();

    // ---- Phase B: GRU1 combine ----
    if (tid < 128) {
      float gr = s_part[0][0][i] + s_part[0][1][i] + s_part[0][2][i] + s_part[0][3][i] + s_bhh1[i];
      float gz = s_part[1][0][i] + s_part[1][1][i] + s_part[1][2][i] + s_part[1][3][i] + s_bhh1[128 + i];
      float gn = s_part[2][0][i] + s_part[2][1][i] + s_part[2][2][i] + s_part[2][3][i] + s_bhh1[256 + i];
      float r = sigm(s_gi1[i] + gr);
      float z = sigm(s_gi1[128 + i] + gz);
      float n = tanhf(s_gi1[256 + i] + r * gn);
      s_h1n[i] = (1.f - z) * n + z * s_h1[i];
    }
    __syncthreads();

    // ---- Phase C: gi2 + gh2 partials ----
    {
      const float4* xn = (const float4*)s_h1n + (jc << 3);
      const float4* xh = (const float4*)s_h2 + (jc << 3);
      float a0 = 0.f, a1 = 0.f, a2 = 0.f, c0 = 0.f, c1 = 0.f, c2 = 0.f;
#pragma unroll
      for (int kk = 0; kk < 4; ++kk) {
        float4 n0 = xn[2 * kk], n1 = xn[2 * kk + 1];
        h2 p0 = __builtin_amdgcn_cvt_pkrtz(n0.x, n0.y);
        h2 p1 = __builtin_amdgcn_cvt_pkrtz(n0.z, n0.w);
        h2 p2 = __builtin_amdgcn_cvt_pkrtz(n1.x, n1.y);
        h2 p3 = __builtin_amdgcn_cvt_pkrtz(n1.z, n1.w);
        float4 h0 = xh[2 * kk], h1v = xh[2 * kk + 1];
        h2 q0 = __builtin_amdgcn_cvt_pkrtz(h0.x, h0.y);
        h2 q1 = __builtin_amdgcn_cvt_pkrtz(h0.z, h0.w);
        h2 q2 = __builtin_amdgcn_cvt_pkrtz(h1v.x, h1v.y);
        h2 q3 = __builtin_amdgcn_cvt_pkrtz(h1v.z, h1v.w);
        uint4 w;
        w = wgt[3][kk]; a0 = fd2(a0, w.x, p0); a0 = fd2(a0, w.y, p1); a0 = fd2(a0, w.z, p2); a0 = fd2(a0, w.w, p3);
        w = wgt[4][kk]; a1 = fd2(a1, w.x, p0); a1 = fd2(a1, w.y, p1); a1 = fd2(a1, w.z, p2); a1 = fd2(a1, w.w, p3);
        w = wgt[5][kk]; a2 = fd2(a2, w.x, p0); a2 = fd2(a2, w.y, p1); a2 = fd2(a2, w.z, p2); a2 = fd2(a2, w.w, p3);
        w = wgt[6][kk]; c0 = fd2(c0, w.x, q0); c0 = fd2(c0, w.y, q1); c0 = fd2(c0, w.z, q2); c0 = fd2(c0, w.w, q3);
        w = wgt[7][kk]; c1 = fd2(c1, w.x, q0); c1 = fd2(c1, w.y, q1); c1 = fd2(c1, w.z, q2); c1 = fd2(c1, w.w, q3);
        w = wgt[8][kk]; c2 = fd2(c2, w.x, q0); c2 = fd2(c2, w.y, q1); c2 = fd2(c2, w.z, q2); c2 = fd2(c2, w.w, q3);
      }
      s_part[0][jc][i] = a0; s_part[1][jc][i] = a1; s_part[2][jc][i] = a2;
      s_part[3][jc][i] = c0; s_part[4][jc][i] = c1; s_part[5][jc][i] = c2;
    }
    __syncthreads();

    // ---- Phase D: GRU2 combine -> g2 ----
    if (tid < 128) {
      float gir = s_part[0][0][i] + s_part[0][1][i] + s_part[0][2][i] + s_part[0][3][i] + s_bih2[i];
      float giz = s_part[1][0][i] + s_part[1][1][i] + s_part[1][2][i] + s_part[1][3][i] + s_bih2[128 + i];
      float gin = s_part[2][0][i] + s_part[2][1][i] + s_part[2][2][i] + s_part[2][3][i] + s_bih2[256 + i];
      float ghr = s_part[3][0][i] + s_part[3][1][i] + s_part[3][2][i] + s_part[3][3][i] + s_bhh2[i];
      float ghz = s_part[4][0][i] + s_part[4][1][i] + s_part[4][2][i] + s_part[4][3][i] + s_bhh2[128 + i];
      float ghn = s_part[5][0][i] + s_part[5][1][i] + s_part[5][2][i] + s_part[5][3][i] + s_bhh2[256 + i];
      float r = sigm(gir + ghr), z = sigm(giz + ghz), n = tanhf(gin + r * ghn);
      s_g2[i] = (1.f - z) * n + z * s_h2[i];
    }
    __syncthreads();

    // ---- Phase E: Qp partials + vh dot/gather ----
    {
      const float4* xg = (const float4*)s_g2 + (jc << 3);
      float aq = 0.f;
#pragma unroll
      for (int kk = 0; kk < 4; ++kk) {
        float4 g0 = xg[2 * kk], g1 = xg[2 * kk + 1];
        h2 p0 = __builtin_amdgcn_cvt_pkrtz(g0.x, g0.y);
        h2 p1 = __builtin_amdgcn_cvt_pkrtz(g0.z, g0.w);
        h2 p2 = __builtin_amdgcn_cvt_pkrtz(g1.x, g1.y);
        h2 p3 = __builtin_amdgcn_cvt_pkrtz(g1.z, g1.w);
        uint4 w = wgt[9][kk];
        aq = fd2(aq, w.x, p0); aq = fd2(aq, w.y, p1); aq = fd2(aq, w.z, p2); aq = fd2(aq, w.w, p3);
      }
      s_part[0][jc][i] = aq;
    }
    if (wv == 7) {
      float pa = s_g2[lane] * wh_lo + s_g2[64 + lane] * wh_hi;
      for (int off = 32; off > 0; off >>= 1) pa += __shfl_down(pa, off);
      if (lane == 0) s_vh[0] = pa;
      if (lane >= 16 && lane < 26) s_vh[1 + lane - 16] = s_vhh[s_tix[lane - 16]];
    }
    __syncthreads();

    // ---- Phase F: Qp reduce ----
    if (tid < 128) {
      s_Qpg2[i] = s_part[0][0][i] + s_part[0][1][i] + s_part[0][2][i] + s_part[0][3][i] + s_bq[i];
    }
    __syncthreads();

    // ---- Phase G: 55 logits ----
    if (tid < 440) {
      int p = tid >> 3, sub = tid & 7;
      int q = p / 5, s = p - q * 5;
      const unsigned* kpr = &s_Kp[s * 66 + sub * 8];
      float a = 0.f;
      if (q == 0) {
        const float* qp = s_Qpg2 + sub * 16;
#pragma unroll
        for (int k = 0; k < 8; ++k) {
          h2 x = __builtin_amdgcn_cvt_pkrtz(qp[2 * k], qp[2 * k + 1]);
          a = fd2(a, kpr[k], x);
        }
      } else {
        int row = s_tix[q - 1];
        int xr = row & 63;
        const unsigned* ro = qph_pk + row * 64;
#pragma unroll
        for (int k = 0; k < 8; ++k) a = fd2u(a, ro[(sub * 8 + k) ^ xr], kpr[k]);
      }
      a += __shfl_down(a, 4);
      a += __shfl_down(a, 2);
      a += __shfl_down(a, 1);
      if (sub == 0) s_logit[p] = s_hm[q] ? a : NEGV;
    } else if (tid < 449) {
      s_logit[55 + tid - 440] = NEGV;
    }
    __syncthreads();

    // ---- Phase H: softmax+out (wave7) ; commits ; prefetch LDS writes ----
    if (wv == 7) {
      float l = s_logit[lane];
      float m = l;
      for (int off = 32; off > 0; off >>= 1) m = fmaxf(m, __shfl_xor(m, off));
      float e = __expf(l - m);
      float v = 0.f;
      if (lane < 55) {
        int q = lane / 5, s = lane - q * 5;
        v = sigm(s_vh[q] + s_vqc[par][s] + s_bw);
      }
      float num = e * v, den = e;
      for (int off = 32; off > 0; off >>= 1) { num += __shfl_xor(num, off); den += __shfl_xor(den, off); }
      if (lane == 0) out[b * SEQL + ((t == 0) ? 0 : (t + 1))] = num / den;
    } else {
      if (tid < 96) ((float4*)s_gi1)[tid] = pf4;
      else if (tid < 416) { int kx = tid - 96, s = kx >> 6, e = kx & 63; s_Kp[s * 66 + e] = pfu; }
      else if (tid < 421) s_vqc[parn][tid - 416] = pfv;
      else if (tid < 431) s_tix[tid - 421] = pfs;
      else if (tid < 441) s_hm[1 + tid - 431] = pfs;
      else if (tid < 446) s_cidn[tid - 441] = pfs;
      if (tid >= 256 && tid < 384) {
        int ii = tid - 256;
        s_h1[ii] = s_h1n[ii];
        if (t > 0) s_h2[ii] = s_g2[ii];
      }
      if (t > 0 && tid >= 96 && tid < 160) {
        int k2 = tid - 96;
        qph_pk[t * 64 + (k2 ^ (t & 63))] = pkh(s_Qpg2[2 * k2], s_Qpg2[2 * k2 + 1]);
      }
      if (tid == 0 && t > 0) s_vhh[t] = s_vh[0];
    }
    __syncthreads();
  }
}

extern "C" void kernel_launch(void* const* d_in, const int* in_sizes, int n_in,
                              void* d_out, int out_size, void* d_ws, size_t ws_size,
                              hipStream_t stream) {
  (void)in_sizes; (void)n_in; (void)out_size; (void)ws_size;
  const int* qseq = (const int*)d_in[0];
  const int* rseq = (const int*)d_in[1];
  const int* mseq = (const int*)d_in[2];
  const int* qnbr = (const int*)d_in[3];
  const int* cnbr = (const int*)d_in[4];
  const int* qctab = (const int*)d_in[5];
  const float* Eq = (const float*)d_in[6];
  const float* Ec = (const float*)d_in[7];
  const float* Er = (const float*)d_in[8];
  const float* W_ih1 = (const float*)d_in[9];
  const float* W_hh1 = (const float*)d_in[10];
  const float* b_ih1 = (const float*)d_in[11];
  const float* b_hh1 = (const float*)d_in[12];
  const float* W_ih2 = (const float*)d_in[13];
  const float* W_hh2 = (const float*)d_in[14];
  const float* b_ih2 = (const float*)d_in[15];
  const float* b_hh2 = (const float*)d_in[16];
  const float* W_agg = (const float*)d_in[17];
  const float* b_agg = (const float*)d_in[18];
  const float* W_agg_last = (const float*)d_in[19];
  const float* b_agg_last = (const float*)d_in[20];
  const float* Wq = (const float*)d_in[21];
  const float* bq = (const float*)d_in[22];
  const float* Wk = (const float*)d_in[23];
  const float* bk = (const float*)d_in[24];
  const float* Ww = (const float*)d_in[25];
  const float* bw = (const float*)d_in[26];
  const float* h1i = (const float*)d_in[27];
  const float* h2i = (const float*)d_in[28];
  float* ws = (float*)d_ws;
  float* out = (float*)d_out;

  hipLaunchKernelGGL(k_prep, dim3(771), dim3(256), 0, stream,
                     W_hh1, W_ih2, W_hh2, Wq, Wk, W_agg, W_agg_last, W_ih1, Er, ws);
  hipLaunchKernelGGL(k_concept, dim3(1000), dim3(128), 0, stream,
                     cnbr, Eq, Ec, b_agg, bk, Ww, ws);
  hipLaunchKernelGGL(k_agg, dim3(BSZ * TST), dim3(128), 0, stream,
                     qseq, rseq, mseq, qnbr, Eq, b_agg, b_agg_last, b_ih1, ws);
  hipLaunchKernelGGL(k_topk, dim3(BSZ * TST), dim3(128), 0, stream,
                     qseq, qctab, Eq, bk, Ww, ws);
  hipLaunchKernelGGL(k_seq, dim3(BSZ), dim3(512), 0, stream,
                     b_hh1, b_ih2, b_hh2, bq, Ww, bw, h1i, h2i, ws, out);
}

// Round 5
// 778.294 us; speedup vs baseline: 8.5061x; 1.1231x over previous
//
#include <hip/hip_runtime.h>

#define DD 128
#define BSZ 128
#define SEQL 128
#define TST 127
#define QNN 4
#define CNN 10
#define NQCC 4
#define RKK 10
#define NEGV -1000000000.0f

// ---- workspace float offsets ----
#define OFF_WTA0    0         // [128][128] W_agg0^T
#define OFF_WTA1    16384     // [128][128] W_agg1^T
#define OFF_WTAL    32768     // [128][128] W_agg_last^T
#define OFF_WTIH1A  49152     // [128][384] W_ih1[:, :128]^T
#define OFF_ERIH1   98304     // [2][384]   W_ih1[:,128:]@Er[r]
#define OFF_WKT     99072     // [128][128] Wk^T
#define OFF_WPACK   115456    // 81920 uints: f16-pair packed W_hh1,W_ih2,W_hh2,Wq
#define OFF_ECA0    197376    // [1000][128] W_agg0 @ Ec[c]
#define OFF_E1C     325376    // [1000][128] tanh(W_agg1@(cmean+Ec)+b1)
#define OFF_KPC     453376    // [1000][64] uints (f16 pairs of Wk@Ec+bk)
#define OFF_VQCC    517376    // [1000] f32 dot(Wqc, Ec[c])
#define OFF_GRAM    518400    // [128][128][128] f32 (dead after k_topk; overlaps GI1)
#define OFF_GI1     518400    // [16256][384]  (written by k_agg AFTER k_topk)
#define OFF_KP0     6760704   // [128][128 s][64] uints (f16 pairs of Wk@Eq[qseq[b,s]]+bk)
#define OFF_VQC0    7809280   // [128][128 s] f32
#define OFF_TIX     7825664   // [16256][10] int
#define OFF_TMSK    7988224   // [16256][10] int
#define OFF_CID     8150784   // [128][128 s][5] int

typedef __fp16 h2 __attribute__((ext_vector_type(2)));

__device__ __forceinline__ float sigm(float x) { return 1.0f / (1.0f + __expf(-x)); }
__device__ __forceinline__ unsigned pkh(float a, float b) {
  h2 v; v.x = (__fp16)a; v.y = (__fp16)b;
  return __builtin_bit_cast(unsigned, v);
}
__device__ __forceinline__ float fd2(float acc, unsigned w, h2 x) {
  return __builtin_amdgcn_fdot2(__builtin_bit_cast(h2, w), x, acc, false);
}
__device__ __forceinline__ float fd2u(float acc, unsigned w, unsigned x) {
  return __builtin_amdgcn_fdot2(__builtin_bit_cast(h2, w), __builtin_bit_cast(h2, x), acc, false);
}

// ---------------- K0a: fp32 tables + f16 packed weight table ----------------
__global__ __launch_bounds__(256) void k_prep(
    const float* __restrict__ W_hh1, const float* __restrict__ W_ih2,
    const float* __restrict__ W_hh2, const float* __restrict__ Wq,
    const float* __restrict__ Wk, const float* __restrict__ W_agg,
    const float* __restrict__ W_agg_last, const float* __restrict__ W_ih1,
    const float* __restrict__ Er, float* __restrict__ ws) {
  int idx = blockIdx.x * 256 + threadIdx.x;
  const int TOT = 197376;
  for (int o = idx; o < TOT; o += gridDim.x * 256) {
    int r = o;
    if (r < 16384) { int j = r >> 7, i = r & 127; ws[OFF_WTA0 + r] = W_agg[i * 128 + j]; continue; }
    r -= 16384;
    if (r < 16384) { int j = r >> 7, i = r & 127; ws[OFF_WTA1 + r] = W_agg[16384 + i * 128 + j]; continue; }
    r -= 16384;
    if (r < 16384) { int j = r >> 7, i = r & 127; ws[OFF_WTAL + r] = W_agg_last[i * 128 + j]; continue; }
    r -= 16384;
    if (r < 49152) { int j = r / 384, i = r % 384; ws[OFF_WTIH1A + r] = W_ih1[i * 256 + j]; continue; }
    r -= 49152;
    if (r < 768) {
      int rr = r / 384, i2 = r % 384;
      float a = 0.f;
      for (int j = 0; j < 128; ++j) a += Er[rr * 128 + j] * W_ih1[i2 * 256 + 128 + j];
      ws[OFF_ERIH1 + r] = a; continue;
    }
    r -= 768;
    if (r < 16384) { int j = r >> 7, i = r & 127; ws[OFF_WKT + r] = Wk[i * 128 + j]; continue; }
    r -= 16384;
    { // WPACK
      int n = r & 3; int q = r >> 2;
      int i = q & 127; q >>= 7;
      int kk = q & 3; q >>= 2;
      int jc = q & 3; int c = q >> 2;
      int j0 = jc * 32 + kk * 8 + n * 2;
      const float* row;
      if (c < 3) row = W_hh1 + (size_t)(c * 128 + i) * 128;
      else if (c < 6) row = W_ih2 + (size_t)((c - 3) * 128 + i) * 128;
      else if (c < 9) row = W_hh2 + (size_t)((c - 6) * 128 + i) * 128;
      else row = Wq + (size_t)i * 128;
      ((unsigned*)ws)[OFF_WPACK + r] = pkh(row[j0], row[j0 + 1]);
    }
  }
}

// ---------------- K0b: per-concept tables (+KpC, vqcC) ----------------
__global__ __launch_bounds__(128) void k_concept(
    const int* __restrict__ cnbr, const float* __restrict__ Eq,
    const float* __restrict__ Ec, const float* __restrict__ b_agg,
    const float* __restrict__ bk, const float* __restrict__ Ww,
    float* __restrict__ ws) {
  int c = blockIdx.x;
  int tid = threadIdx.x;
  __shared__ int s_nb[CNN];
  __shared__ float s_v[DD], s_ec[DD], s_t2[DD], s_w2[DD];
  if (tid < CNN) s_nb[tid] = cnbr[c * CNN + tid];
  __syncthreads();
  float ec = Ec[c * DD + tid];
  float cm = 0.f;
#pragma unroll
  for (int l = 0; l < CNN; ++l) cm += Eq[(size_t)s_nb[l] * DD + tid];
  s_ec[tid] = ec;
  s_v[tid] = cm * 0.1f + ec;
  __syncthreads();
  const float* WtA0 = ws + OFF_WTA0;
  const float* WtA1 = ws + OFF_WTA1;
  const float* WkT = ws + OFF_WKT;
  float a1 = 0.f, a0 = 0.f, kc = 0.f;
#pragma unroll 8
  for (int j = 0; j < DD; ++j) {
    a1 += WtA1[j * DD + tid] * s_v[j];
    a0 += WtA0[j * DD + tid] * s_ec[j];
    kc += WkT[j * DD + tid] * s_ec[j];
  }
  ws[OFF_E1C + c * DD + tid] = tanhf(a1 + b_agg[DD + tid]);
  ws[OFF_ECA0 + c * DD + tid] = a0;
  s_t2[tid] = kc + bk[tid];
  s_w2[tid] = s_ec[tid] * Ww[128 + tid];
  __syncthreads();
  if (tid < 64) {
    ((unsigned*)ws)[OFF_KPC + c * 64 + tid] = pkh(s_t2[2 * tid], s_t2[2 * tid + 1]);
    float pa = s_w2[tid] + s_w2[tid + 64];
    for (int off = 32; off > 0; off >>= 1) pa += __shfl_down(pa, off);
    if (tid == 0) ws[OFF_VQCC + c] = pa;
  }
}

// ---------------- K1: per-b Gram + KpX + vqc0 ----------------
__global__ __launch_bounds__(256) void k_gram(
    const int* __restrict__ qseq, const float* __restrict__ Eq,
    const float* __restrict__ bk, const float* __restrict__ Ww,
    float* __restrict__ ws) {
  int b = blockIdx.x;
  int tid = threadIdx.x;
  __shared__ float sX[128][129];
  __shared__ float s_tmp[2][8][DD];
  __shared__ int sq[SEQL];
  __shared__ float sbk[DD], sWqc[DD];
  if (tid < 128) { sq[tid] = qseq[b * SEQL + tid]; sbk[tid] = bk[tid]; sWqc[tid] = Ww[128 + tid]; }
  __syncthreads();
  for (int o = tid; o < 128 * 32; o += 256) {
    int s = o >> 5, p = o & 31;
    float4 v = ((const float4*)(Eq + (size_t)sq[s] * DD))[p];
    sX[s][p * 4] = v.x; sX[s][p * 4 + 1] = v.y; sX[s][p * 4 + 2] = v.z; sX[s][p * 4 + 3] = v.w;
  }
  __syncthreads();
  // Gram: 16x16 thread grid, 8x8 tiles
  {
    int r0 = (tid >> 4) * 8, c0 = (tid & 15) * 8;
    float acc[8][8];
#pragma unroll
    for (int u = 0; u < 8; ++u)
#pragma unroll
      for (int v = 0; v < 8; ++v) acc[u][v] = 0.f;
    for (int k = 0; k < 128; ++k) {
      float a[8], bb[8];
#pragma unroll
      for (int u = 0; u < 8; ++u) { a[u] = sX[r0 + u][k]; bb[u] = sX[c0 + u][k]; }
#pragma unroll
      for (int u = 0; u < 8; ++u)
#pragma unroll
        for (int v = 0; v < 8; ++v) acc[u][v] = fmaf(a[u], bb[v], acc[u][v]);
    }
    float* gb = ws + OFF_GRAM + (size_t)b * 16384;
#pragma unroll
    for (int u = 0; u < 8; ++u) {
      float4 v0 = {acc[u][0], acc[u][1], acc[u][2], acc[u][3]};
      float4 v1 = {acc[u][4], acc[u][5], acc[u][6], acc[u][7]};
      ((float4*)(gb + (size_t)(r0 + u) * 128 + c0))[0] = v0;
      ((float4*)(gb + (size_t)(r0 + u) * 128 + c0 + 4))[0] = v1;
    }
  }
  // KpX: out[s][i] = Wk@X[s] + bk, packed f16 pairs
  {
    const float* WkT = ws + OFF_WKT;
    unsigned* KP0 = (unsigned*)ws + OFF_KP0;
    int i = tid & 127, half = tid >> 7;
    int s0 = half * 64;
    for (int sb = 0; sb < 64; sb += 8) {
      float acc[8];
#pragma unroll
      for (int u = 0; u < 8; ++u) acc[u] = 0.f;
      for (int j = 0; j < DD; ++j) {
        float w = WkT[j * DD + i];
#pragma unroll
        for (int u = 0; u < 8; ++u) acc[u] = fmaf(w, sX[s0 + sb + u][j], acc[u]);
      }
      __syncthreads();
#pragma unroll
      for (int u = 0; u < 8; ++u) s_tmp[half][u][i] = acc[u] + sbk[i];
      __syncthreads();
      for (int o = tid; o < 16 * 64; o += 256) {
        int rr = o >> 6, e = o & 63;
        int hh = rr >> 3, uu = rr & 7;
        int s = hh * 64 + sb + uu;
        KP0[((size_t)b * 128 + s) * 64 + e] = pkh(s_tmp[hh][uu][2 * e], s_tmp[hh][uu][2 * e + 1]);
      }
      __syncthreads();
    }
  }
  // vqc0[s] = dot(Wqc, X[s])
  if (tid < 128) {
    float a = 0.f;
    for (int j = 0; j < DD; ++j) a = fmaf(sX[tid][j], sWqc[j], a);
    ws[OFF_VQC0 + b * 128 + tid] = a;
  }
}

// ---------------- K2: top-10 from gram row + cid ----------------
__global__ __launch_bounds__(128) void k_topk(
    const int* __restrict__ qseq, const int* __restrict__ qctab,
    float* __restrict__ ws) {
  int* tix = (int*)(ws + OFF_TIX);
  int* tmsk = (int*)(ws + OFF_TMSK);
  int* cid = (int*)(ws + OFF_CID);
  int bt = blockIdx.x;
  int b = bt / TST, t = bt - b * TST;
  int tid = threadIdx.x;
  int lane = tid & 63, wv = tid >> 6;
  __shared__ float s_sc[SEQL];
  __shared__ float s_wv[2];
  __shared__ int s_wi[2];
  if (tid < 5) {
    int qn = qseq[b * SEQL + t + 1];
    cid[(b * 128 + t + 1) * 5 + tid] = (tid == 0) ? qn : qctab[qn * NQCC + tid - 1];
  }
  const float* grow = ws + OFF_GRAM + ((size_t)b * 128 + (t + 1)) * 128;
  s_sc[tid] = (tid < t) ? grow[tid] : NEGV;
  __syncthreads();
  for (int k = 0; k < RKK; ++k) {
    float v = s_sc[tid];
    int ix = tid;
    for (int off = 32; off > 0; off >>= 1) {
      float ov = __shfl_down(v, off);
      int oi = __shfl_down(ix, off);
      if (ov > v || (ov == v && oi < ix)) { v = ov; ix = oi; }
    }
    if (lane == 0) { s_wv[wv] = v; s_wi[wv] = ix; }
    __syncthreads();
    if (tid == 0) {
      float v0 = s_wv[0], v1 = s_wv[1];
      int i0 = s_wi[0], i1 = s_wi[1];
      if (v1 > v0 || (v1 == v0 && i1 < i0)) { v0 = v1; i0 = i1; }
      tix[bt * RKK + k] = i0;
      tmsk[bt * RKK + k] = (v0 > NEGV * 0.5f) ? 1 : 0;
      s_sc[i0] = -__builtin_inff();
    }
    __syncthreads();
  }
}

// ---------------- K3: batched aggregation + gi1 (8 t per block) ----------------
__global__ __launch_bounds__(128) void k_agg(
    const int* __restrict__ qseq, const int* __restrict__ rseq,
    const int* __restrict__ mseq, const int* __restrict__ qnbr,
    const float* __restrict__ Eq, const float* __restrict__ b_agg,
    const float* __restrict__ b_agg_last, const float* __restrict__ b_ih1,
    float* __restrict__ ws) {
  int blk = blockIdx.x;
  int b = blk >> 4, g = blk & 15;
  int t0 = g * 8;
  int nu = (t0 + 8 <= TST) ? 8 : (TST - t0);
  int tid = threadIdx.x;
  __shared__ float s_a[8][DD], s_b[8][DD], s_c[8][DD];
  __shared__ int s_q[8], s_r[8], s_m[8];
  __shared__ int s_n1[8][QNN];
  if (tid < 8) {
    int ok = tid < nu;
    int idx = b * SEQL + (ok ? (t0 + tid) : 0);
    s_q[tid] = qseq[idx];
    s_r[tid] = ok ? rseq[idx] : 0;
    s_m[tid] = ok ? mseq[idx] : 0;
  }
  __syncthreads();
  if (tid < 32) { int u = tid >> 2, k = tid & 3; s_n1[u][k] = qnbr[s_q[u] * QNN + k]; }
  for (int o = tid; o < 8 * 32; o += 128) {
    int u = o >> 5, p = o & 31;
    float4 v = ((const float4*)(Eq + (size_t)s_q[u] * DD))[p];
    s_a[u][p * 4] = v.x; s_a[u][p * 4 + 1] = v.y; s_a[u][p * 4 + 2] = v.z; s_a[u][p * 4 + 3] = v.w;
  }
  __syncthreads();
  const float* WtA0 = ws + OFF_WTA0;
  const float* WtAL = ws + OFF_WTAL;
  const float* WtIH1A = ws + OFF_WTIH1A;
  const float* EcA0 = ws + OFF_ECA0;
  const float* E1C = ws + OFF_E1C;
  float acc[8];
#pragma unroll
  for (int u = 0; u < 8; ++u) acc[u] = 0.f;
  for (int j = 0; j < DD; ++j) {
    float w = WtA0[j * DD + tid];
#pragma unroll
    for (int u = 0; u < 8; ++u) acc[u] = fmaf(w, s_a[u][j], acc[u]);
  }
  float bat = b_agg[tid];
#pragma unroll
  for (int u = 0; u < 8; ++u) {
    int n0 = s_n1[u][0], n1 = s_n1[u][1], n2 = s_n1[u][2], n3 = s_n1[u][3];
    float pre0 = 0.25f * (EcA0[n0 * DD + tid] + EcA0[n1 * DD + tid] + EcA0[n2 * DD + tid] + EcA0[n3 * DD + tid]);
    float e0 = tanhf(acc[u] + pre0 + bat);
    float e1m = 0.25f * (E1C[n0 * DD + tid] + E1C[n1 * DD + tid] + E1C[n2 * DD + tid] + E1C[n3 * DD + tid]);
    s_b[u][tid] = e1m + e0;
  }
  __syncthreads();
#pragma unroll
  for (int u = 0; u < 8; ++u) acc[u] = 0.f;
  for (int j = 0; j < DD; ++j) {
    float w = WtA0[j * DD + tid];
#pragma unroll
    for (int u = 0; u < 8; ++u) acc[u] = fmaf(w, s_b[u][j], acc[u]);
  }
#pragma unroll
  for (int u = 0; u < 8; ++u) s_c[u][tid] = tanhf(acc[u] + bat);
  __syncthreads();
#pragma unroll
  for (int u = 0; u < 8; ++u) acc[u] = 0.f;
  for (int j = 0; j < DD; ++j) {
    float w = WtAL[j * DD + tid];
#pragma unroll
    for (int u = 0; u < 8; ++u) acc[u] = fmaf(w, s_c[u][j], acc[u]);
  }
  float balt = b_agg_last[tid];
#pragma unroll
  for (int u = 0; u < 8; ++u) {
    float aggv = tanhf(acc[u] + balt);
    s_b[u][tid] = s_m[u] ? aggv : s_a[u][tid];
  }
  __syncthreads();
  float g0[8], g1[8], g2[8];
#pragma unroll
  for (int u = 0; u < 8; ++u) { g0[u] = 0.f; g1[u] = 0.f; g2[u] = 0.f; }
  for (int j = 0; j < DD; ++j) {
    float w0 = WtIH1A[j * 384 + tid];
    float w1 = WtIH1A[j * 384 + 128 + tid];
    float w2 = WtIH1A[j * 384 + 256 + tid];
#pragma unroll
    for (int u = 0; u < 8; ++u) {
      float x = s_b[u][j];
      g0[u] = fmaf(w0, x, g0[u]);
      g1[u] = fmaf(w1, x, g1[u]);
      g2[u] = fmaf(w2, x, g2[u]);
    }
  }
  for (int u = 0; u < nu; ++u) {
    const float* ErI = ws + OFF_ERIH1 + s_r[u] * 384;
    float* gi1 = ws + OFF_GI1 + (size_t)(b * TST + t0 + u) * 384;
    gi1[tid] = g0[u] + ErI[tid] + b_ih1[tid];
    gi1[128 + tid] = g1[u] + ErI[128 + tid] + b_ih1[128 + tid];
    gi1[256 + tid] = g2[u] + ErI[256 + tid] + b_ih1[256 + tid];
  }
}

// ---------------- K4: sequential scan, f16 register-resident weights ----------------
__global__ __launch_bounds__(512) __attribute__((amdgpu_waves_per_eu(2, 2))) void k_seq(
    const float* __restrict__ b_hh1, const float* __restrict__ b_ih2,
    const float* __restrict__ b_hh2, const float* __restrict__ bq,
    const float* __restrict__ Ww, const float* __restrict__ bw,
    const float* __restrict__ h1i, const float* __restrict__ h2i,
    float* __restrict__ ws, float* __restrict__ out) {
  const int tid = threadIdx.x;
  const int b = blockIdx.x;
  const int i = tid & 127, jc = tid >> 7;
  const int lane = tid & 63, wv = tid >> 6;
  const int bt0 = b * TST;

  const float4* gi1f4 = (const float4*)(ws + OFF_GI1);
  const unsigned* Kp0pk = (const unsigned*)ws + OFF_KP0;
  const unsigned* KpCpk = (const unsigned*)ws + OFF_KPC;
  const float* vqc0_all = ws + OFF_VQC0;
  const float* vqcC_all = ws + OFF_VQCC;
  const int* tix_all = (const int*)(ws + OFF_TIX);
  const int* tmsk_all = (const int*)(ws + OFF_TMSK);
  const int* cid_all = (const int*)(ws + OFF_CID);
  const uint4* wp = (const uint4*)((const unsigned*)ws + OFF_WPACK);

  __shared__ float s_h1[DD], s_h2[DD], s_h1n[DD], s_g2[DD], s_Qpg2[DD];
  __shared__ float s_part[6][4][DD];
  __shared__ unsigned qph_pk[SEQL * 64];  // f16-pair Qp history, XOR(row&63)-swizzled
  __shared__ unsigned s_Kp[5 * 66];
  __shared__ float s_gi1[384];
  __shared__ float s_vhh[SEQL];
  __shared__ float s_logit[64];
  __shared__ float s_bhh1[384], s_bih2[384], s_bhh2[384], s_bq[DD];
  __shared__ float s_vh[11], s_vqc[2][5], s_bw;
  __shared__ int s_tix[RKK], s_hm[11], s_cidn[5];

  // --- weights -> registers: 10 chunks x 4 uint4 = 160 VGPR ---
  uint4 wgt[10][4];
#pragma unroll
  for (int c = 0; c < 10; ++c)
#pragma unroll
    for (int kk = 0; kk < 4; ++kk)
      wgt[c][kk] = wp[((c * 4 + jc) * 4 + kk) * 128 + i];

  // --- prologue ---
  for (int o = tid; o < 384; o += 512) { s_bhh1[o] = b_hh1[o]; s_bih2[o] = b_ih2[o]; s_bhh2[o] = b_hh2[o]; }
  if (tid < 128) { s_bq[tid] = bq[tid]; s_h1[tid] = h1i[b * DD + tid]; s_h2[tid] = h2i[b * DD + tid]; s_vhh[tid] = 0.f; }
  float wh_lo = 0.f, wh_hi = 0.f;
  if (wv == 7) { wh_lo = Ww[lane]; wh_hi = Ww[64 + lane]; }
  if (tid == 0) { s_bw = bw[0]; out[b * SEQL + 1] = 0.f; s_hm[0] = 1; }
  if (tid >= 8 && tid < 13) s_cidn[tid - 8] = cid_all[(b * 128 + 1) * 5 + tid - 8];
  if (tid >= 16 && tid < 26) s_tix[tid - 16] = tix_all[bt0 * RKK + tid - 16];
  if (tid >= 32 && tid < 42) s_hm[1 + tid - 32] = tmsk_all[bt0 * RKK + tid - 32];
  __syncthreads();
  for (int o = tid; o < SEQL * 64; o += 512) {
    int row = o >> 6, k = o & 63;
    qph_pk[row * 64 + (k ^ (row & 63))] = pkh(s_bq[2 * k], s_bq[2 * k + 1]);
  }
  if (tid < 96) ((float4*)s_gi1)[tid] = gi1f4[(size_t)bt0 * 96 + tid];
  else if (tid < 416) {
    int kx = tid - 96, s = kx >> 6, e = kx & 63;
    s_Kp[s * 66 + e] = (s == 0) ? Kp0pk[(size_t)(b * 128 + 1) * 64 + e] : KpCpk[s_cidn[s] * 64 + e];
  } else if (tid < 421) {
    int s = tid - 416;
    s_vqc[0][s] = (s == 0) ? vqc0_all[b * 128 + 1] : vqcC_all[s_cidn[s]];
  }
  __syncthreads();
  if (tid < 5) s_cidn[tid] = cid_all[(b * 128 + 2) * 5 + tid];
  __syncthreads();

  for (int t = 0; t < TST; ++t) {
    const int par = t & 1, parn = par ^ 1;
    const int tpn = (t + 1 < TST) ? t + 1 : TST - 1;
    const int tpp = (t + 2 < TST) ? t + 2 : TST - 1;
    float4 pf4 = {0.f, 0.f, 0.f, 0.f};
    unsigned pfu = 0; int pfs = 0; float pfv = 0.f;

    // ---- Phase A: prefetch issue + gh1 partials ----
    if (tid < 96) pf4 = gi1f4[(size_t)(bt0 + tpn) * 96 + tid];
    else if (tid < 416) {
      int kx = tid - 96, s = kx >> 6, e = kx & 63;
      pfu = (s == 0) ? Kp0pk[(size_t)(b * 128 + tpn + 1) * 64 + e] : KpCpk[s_cidn[s] * 64 + e];
    } else if (tid < 421) {
      int s = tid - 416;
      pfv = (s == 0) ? vqc0_all[b * 128 + tpn + 1] : vqcC_all[s_cidn[s]];
    } else if (tid < 431) pfs = tix_all[(bt0 + tpn) * RKK + tid - 421];
    else if (tid < 441) pfs = tmsk_all[(bt0 + tpn) * RKK + tid - 431];
    else if (tid < 446) pfs = cid_all[(b * 128 + tpp + 1) * 5 + tid - 441];
    {
      const float4* xp = (const float4*)s_h1 + (jc << 3);
      float a0 = 0.f, a1 = 0.f, a2 = 0.f;
#pragma unroll
      for (int kk = 0; kk < 4; ++kk) {
        float4 x0 = xp[2 * kk], x1 = xp[2 * kk + 1];
        h2 p0 = __builtin_amdgcn_cvt_pkrtz(x0.x, x0.y);
        h2 p1 = __builtin_amdgcn_cvt_pkrtz(x0.z, x0.w);
        h2 p2 = __builtin_amdgcn_cvt_pkrtz(x1.x, x1.y);
        h2 p3 = __builtin_amdgcn_cvt_pkrtz(x1.z, x1.w);
        uint4 w;
        w = wgt[0][kk]; a0 = fd2(a0, w.x, p0); a0 = fd2(a0, w.y, p1); a0 = fd2(a0, w.z, p2); a0 = fd2(a0, w.w, p3);
        w = wgt[1][kk]; a1 = fd2(a1, w.x, p0); a1 = fd2(a1, w.y, p1); a1 = fd2(a1, w.z, p2); a1 = fd2(a1, w.w, p3);
        w = wgt[2][kk]; a2 = fd2(a2, w.x, p0); a2 = fd2(a2, w.y, p1); a2 = fd2(a2, w.z, p2); a2 = fd2(a2, w.w, p3);
      }
      s_part[0][jc][i] = a0; s_part[1][jc][i] = a1; s_part[2][jc][i] = a2;
    }
    __syncthreads();

    // ---- Phase B: GRU1 combine ----
    if (tid < 128) {
      float gr = s_part[0][0][i] + s_part[0][1][i] + s_part[0][2][i] + s_part[0][3][i] + s_bhh1[i];
      float gz = s_part[1][0][i] + s_part[1][1][i] + s_part[1][2][i] + s_part[1][3][i] + s_bhh1[128 + i];
      float gn = s_part[2][0][i] + s_part[2][1][i] + s_part[2][2][i] + s_part[2][3][i] + s_bhh1[256 + i];
      float r = sigm(s_gi1[i] + gr);
      float z = sigm(s_gi1[128 + i] + gz);
      float n = tanhf(s_gi1[256 + i] + r * gn);
      s_h1n[i] = (1.f - z) * n + z * s_h1[i];
    }
    __syncthreads();

    // ---- Phase C: gi2 + gh2 partials ----
    {
      const float4* xn = (const float4*)s_h1n + (jc << 3);
      const float4* xh = (const float4*)s_h2 + (jc << 3);
      float a0 = 0.f, a1 = 0.f, a2 = 0.f, c0 = 0.f, c1 = 0.f, c2 = 0.f;
#pragma unroll
      for (int kk = 0; kk < 4; ++kk) {
        float4 n0 = xn[2 * kk], n1 = xn[2 * kk + 1];
        h2 p0 = __builtin_amdgcn_cvt_pkrtz(n0.x, n0.y);
        h2 p1 = __builtin_amdgcn_cvt_pkrtz(n0.z, n0.w);
        h2 p2 = __builtin_amdgcn_cvt_pkrtz(n1.x, n1.y);
        h2 p3 = __builtin_amdgcn_cvt_pkrtz(n1.z, n1.w);
        float4 h0 = xh[2 * kk], h1v = xh[2 * kk + 1];
        h2 q0 = __builtin_amdgcn_cvt_pkrtz(h0.x, h0.y);
        h2 q1 = __builtin_amdgcn_cvt_pkrtz(h0.z, h0.w);
        h2 q2 = __builtin_amdgcn_cvt_pkrtz(h1v.x, h1v.y);
        h2 q3 = __builtin_amdgcn_cvt_pkrtz(h1v.z, h1v.w);
        uint4 w;
        w = wgt[3][kk]; a0 = fd2(a0, w.x, p0); a0 = fd2(a0, w.y, p1); a0 = fd2(a0, w.z, p2); a0 = fd2(a0, w.w, p3);
        w = wgt[4][kk]; a1 = fd2(a1, w.x, p0); a1 = fd2(a1, w.y, p1); a1 = fd2(a1, w.z, p2); a1 = fd2(a1, w.w, p3);
        w = wgt[5][kk]; a2 = fd2(a2, w.x, p0); a2 = fd2(a2, w.y, p1); a2 = fd2(a2, w.z, p2); a2 = fd2(a2, w.w, p3);
        w = wgt[6][kk]; c0 = fd2(c0, w.x, q0); c0 = fd2(c0, w.y, q1); c0 = fd2(c0, w.z, q2); c0 = fd2(c0, w.w, q3);
        w = wgt[7][kk]; c1 = fd2(c1, w.x, q0); c1 = fd2(c1, w.y, q1); c1 = fd2(c1, w.z, q2); c1 = fd2(c1, w.w, q3);
        w = wgt[8][kk]; c2 = fd2(c2, w.x, q0); c2 = fd2(c2, w.y, q1); c2 = fd2(c2, w.z, q2); c2 = fd2(c2, w.w, q3);
      }
      s_part[0][jc][i] = a0; s_part[1][jc][i] = a1; s_part[2][jc][i] = a2;
      s_part[3][jc][i] = c0; s_part[4][jc][i] = c1; s_part[5][jc][i] = c2;
    }
    __syncthreads();

    // ---- Phase D: GRU2 combine -> g2 ----
    if (tid < 128) {
      float gir = s_part[0][0][i] + s_part[0][1][i] + s_part[0][2][i] + s_part[0][3][i] + s_bih2[i];
      float giz = s_part[1][0][i] + s_part[1][1][i] + s_part[1][2][i] + s_part[1][3][i] + s_bih2[128 + i];
      float gin = s_part[2][0][i] + s_part[2][1][i] + s_part[2][2][i] + s_part[2][3][i] + s_bih2[256 + i];
      float ghr = s_part[3][0][i] + s_part[3][1][i] + s_part[3][2][i] + s_part[3][3][i] + s_bhh2[i];
      float ghz = s_part[4][0][i] + s_part[4][1][i] + s_part[4][2][i] + s_part[4][3][i] + s_bhh2[128 + i];
      float ghn = s_part[5][0][i] + s_part[5][1][i] + s_part[5][2][i] + s_part[5][3][i] + s_bhh2[256 + i];
      float r = sigm(gir + ghr), z = sigm(giz + ghz), n = tanhf(gin + r * ghn);
      s_g2[i] = (1.f - z) * n + z * s_h2[i];
    }
    __syncthreads();

    // ---- Phase E: Qp partials + vh dot/gather ----
    {
      const float4* xg = (const float4*)s_g2 + (jc << 3);
      float aq = 0.f;
#pragma unroll
      for (int kk = 0; kk < 4; ++kk) {
        float4 g0 = xg[2 * kk], g1 = xg[2 * kk + 1];
        h2 p0 = __builtin_amdgcn_cvt_pkrtz(g0.x, g0.y);
        h2 p1 = __builtin_amdgcn_cvt_pkrtz(g0.z, g0.w);
        h2 p2 = __builtin_amdgcn_cvt_pkrtz(g1.x, g1.y);
        h2 p3 = __builtin_amdgcn_cvt_pkrtz(g1.z, g1.w);
        uint4 w = wgt[9][kk];
        aq = fd2(aq, w.x, p0); aq = fd2(aq, w.y, p1); aq = fd2(aq, w.z, p2); aq = fd2(aq, w.w, p3);
      }
      s_part[0][jc][i] = aq;
    }
    if (wv == 7) {
      float pa = s_g2[lane] * wh_lo + s_g2[64 + lane] * wh_hi;
      for (int off = 32; off > 0; off >>= 1) pa += __shfl_down(pa, off);
      if (lane == 0) s_vh[0] = pa;
      if (lane >= 16 && lane < 26) s_vh[1 + lane - 16] = s_vhh[s_tix[lane - 16]];
    }
    __syncthreads();

    // ---- Phase F: Qp reduce ----
    if (tid < 128) {
      s_Qpg2[i] = s_part[0][0][i] + s_part[0][1][i] + s_part[0][2][i] + s_part[0][3][i] + s_bq[i];
    }
    __syncthreads();

    // ---- Phase G: 55 logits ----
    if (tid < 440) {
      int p = tid >> 3, sub = tid & 7;
      int q = p / 5, s = p - q * 5;
      const unsigned* kpr = &s_Kp[s * 66 + sub * 8];
      float a = 0.f;
      if (q == 0) {
        const float* qp = s_Qpg2 + sub * 16;
#pragma unroll
        for (int k = 0; k < 8; ++k) {
          h2 x = __builtin_amdgcn_cvt_pkrtz(qp[2 * k], qp[2 * k + 1]);
          a = fd2(a, kpr[k], x);
        }
      } else {
        int row = s_tix[q - 1];
        int xr = row & 63;
        const unsigned* ro = qph_pk + row * 64;
#pragma unroll
        for (int k = 0; k < 8; ++k) a = fd2u(a, ro[(sub * 8 + k) ^ xr], kpr[k]);
      }
      a += __shfl_down(a, 4);
      a += __shfl_down(a, 2);
      a += __shfl_down(a, 1);
      if (sub == 0) s_logit[p] = s_hm[q] ? a : NEGV;
    } else if (tid < 449) {
      s_logit[55 + tid - 440] = NEGV;
    }
    __syncthreads();

    // ---- Phase H: softmax+out (wave7) ; commits ; prefetch LDS writes ----
    if (wv == 7) {
      float l = s_logit[lane];
      float m = l;
      for (int off = 32; off > 0; off >>= 1) m = fmaxf(m, __shfl_xor(m, off));
      float e = __expf(l - m);
      float v = 0.f;
      if (lane < 55) {
        int q = lane / 5, s = lane - q * 5;
        v = sigm(s_vh[q] + s_vqc[par][s] + s_bw);
      }
      float num = e * v, den = e;
      for (int off = 32; off > 0; off >>= 1) { num += __shfl_xor(num, off); den += __shfl_xor(den, off); }
      if (lane == 0) out[b * SEQL + ((t == 0) ? 0 : (t + 1))] = num / den;
    } else {
      if (tid < 96) ((float4*)s_gi1)[tid] = pf4;
      else if (tid < 416) { int kx = tid - 96, s = kx >> 6, e = kx & 63; s_Kp[s * 66 + e] = pfu; }
      else if (tid < 421) s_vqc[parn][tid - 416] = pfv;
      else if (tid < 431) s_tix[tid - 421] = pfs;
      else if (tid < 441) s_hm[1 + tid - 431] = pfs;
      else if (tid < 446) s_cidn[tid - 441] = pfs;
      if (tid >= 256 && tid < 384) {
        int ii = tid - 256;
        s_h1[ii] = s_h1n[ii];
        if (t > 0) s_h2[ii] = s_g2[ii];
      }
      if (t > 0 && tid >= 96 && tid < 160) {
        int k2 = tid - 96;
        qph_pk[t * 64 + (k2 ^ (t & 63))] = pkh(s_Qpg2[2 * k2], s_Qpg2[2 * k2 + 1]);
      }
      if (tid == 0 && t > 0) s_vhh[t] = s_vh[0];
    }
    __syncthreads();
  }
}

extern "C" void kernel_launch(void* const* d_in, const int* in_sizes, int n_in,
                              void* d_out, int out_size, void* d_ws, size_t ws_size,
                              hipStream_t stream) {
  (void)in_sizes; (void)n_in; (void)out_size; (void)ws_size;
  const int* qseq = (const int*)d_in[0];
  const int* rseq = (const int*)d_in[1];
  const int* mseq = (const int*)d_in[2];
  const int* qnbr = (const int*)d_in[3];
  const int* cnbr = (const int*)d_in[4];
  const int* qctab = (const int*)d_in[5];
  const float* Eq = (const float*)d_in[6];
  const float* Ec = (const float*)d_in[7];
  const float* Er = (const float*)d_in[8];
  const float* W_ih1 = (const float*)d_in[9];
  const float* W_hh1 = (const float*)d_in[10];
  const float* b_ih1 = (const float*)d_in[11];
  const float* b_hh1 = (const float*)d_in[12];
  const float* W_ih2 = (const float*)d_in[13];
  const float* W_hh2 = (const float*)d_in[14];
  const float* b_ih2 = (const float*)d_in[15];
  const float* b_hh2 = (const float*)d_in[16];
  const float* W_agg = (const float*)d_in[17];
  const float* b_agg = (const float*)d_in[18];
  const float* W_agg_last = (const float*)d_in[19];
  const float* b_agg_last = (const float*)d_in[20];
  const float* Wq = (const float*)d_in[21];
  const float* bq = (const float*)d_in[22];
  const float* Wk = (const float*)d_in[23];
  const float* bk = (const float*)d_in[24];
  const float* Ww = (const float*)d_in[25];
  const float* bw = (const float*)d_in[26];
  const float* h1i = (const float*)d_in[27];
  const float* h2i = (const float*)d_in[28];
  float* ws = (float*)d_ws;
  float* out = (float*)d_out;

  hipLaunchKernelGGL(k_prep, dim3(771), dim3(256), 0, stream,
                     W_hh1, W_ih2, W_hh2, Wq, Wk, W_agg, W_agg_last, W_ih1, Er, ws);
  hipLaunchKernelGGL(k_concept, dim3(1000), dim3(128), 0, stream,
                     cnbr, Eq, Ec, b_agg, bk, Ww, ws);
  hipLaunchKernelGGL(k_gram, dim3(BSZ), dim3(256), 0, stream,
                     qseq, Eq, bk, Ww, ws);
  hipLaunchKernelGGL(k_topk, dim3(BSZ * TST), dim3(128), 0, stream,
                     qseq, qctab, ws);
  hipLaunchKernelGGL(k_agg, dim3(BSZ * 16), dim3(128), 0, stream,
                     qseq, rseq, mseq, qnbr, Eq, b_agg, b_agg_last, b_ih1, ws);
  hipLaunchKernelGGL(k_seq, dim3(BSZ), dim3(512), 0, stream,
                     b_hh1, b_ih2, b_hh2, bq, Ww, bw, h1i, h2i, ws, out);
}